// Round 1
// baseline (1380.165 us; speedup 1.0000x reference)
//
#include <hip/hip_runtime.h>
#include <math.h>

#define B 2
#define T 4096
#define D 1024
#define DH 32
#define NC 8      // column chunks of 512
#define NT 64     // row tiles of 64

// ---------------- K0: per-batch column sums (for the t=0 row) ----------------
__global__ void mean_kernel(const float* __restrict__ x, float* __restrict__ meansum)
{
    int gid  = blockIdx.x;           // B * 4 dblk * 16 tch = 128 blocks
    int b    = gid >> 6;
    int rem  = gid & 63;
    int dblk = rem >> 4;
    int tch  = rem & 15;
    int d = dblk * 256 + threadIdx.x;
    const float* xp = x + (b * T + tch * 256) * D + d;
    float s = 0.f;
    #pragma unroll 8
    for (int it = 0; it < 256; ++it) s += xp[it * D];
    atomicAdd(&meansum[(b << 10) + d], s);
}

// ---------------- K1: q/k projections ----------------
__global__ __launch_bounds__(256) void qk_kernel(const float* __restrict__ x,
        const float* __restrict__ Wq, const float* __restrict__ Wk,
        float* __restrict__ qo, float* __restrict__ ko)
{
    __shared__ __align__(16) float xs[4 * D];
    int tid = threadIdx.x;
    int row0 = blockIdx.x * 4;                 // 4 global rows (b*T+t) per block
    const float4* src = (const float4*)(x + row0 * D);
    float4* dst = (float4*)xs;
    #pragma unroll
    for (int p = 0; p < 4; ++p) dst[p * 256 + tid] = src[p * 256 + tid];
    __syncthreads();
    int w = tid >> 6, lane = tid & 63;
    int r = row0 + w;
    const float* W = (lane < DH) ? (Wq + lane * D) : (Wk + (lane - DH) * D);
    const float4* W4 = (const float4*)W;
    const float4* xr = (const float4*)(xs + w * D);
    float s = 0.f;
    #pragma unroll 4
    for (int d4 = 0; d4 < D / 4; ++d4) {
        float4 a = xr[d4]; float4 ww = W4[d4];
        s += a.x * ww.x + a.y * ww.y + a.z * ww.z + a.w * ww.w;
    }
    if (lane < DH) qo[r * DH + lane] = s;
    else           ko[r * DH + (lane - DH)] = s;
}

// ---------------- K2: fp32 sim GEMM + running per-row top-8 (per 512-col chunk) ----
// grid: b * rowtile(64 rows) * colchunk(512 cols) = 2*64*8 = 1024 blocks, 256 thr
__global__ __launch_bounds__(256) void topk_kernel(const float* __restrict__ x,
        float* __restrict__ pvals, int* __restrict__ pidx)
{
    // staging As/Bs: [32][68] each (k-major, pad 4 -> <=2-way conflicts, b128-aligned)
    // S (64x65) aliases the staging area; topv/topi live after it.
    __shared__ __align__(16) float lds[4352 + 512];
    __shared__ int topi[512];
    float* As = lds;            // 32*68 = 2176
    float* Bs = lds + 2176;     // 32*68
    float* S  = lds;            // 64*65 = 4160 (aliases staging, barrier-separated)
    float* topv = lds + 4352;

    int tid = threadIdx.x;
    int b   = blockIdx.x >> 9;
    int rem = blockIdx.x & 511;
    int t0  = (rem >> 3) << 6;   // row tile base
    int c0  = (rem & 7) << 9;    // col chunk base
    if (c0 > t0) return;         // no causal cols in this chunk for these rows

    topv[tid] = -INFINITY; topv[tid + 256] = -INFINITY;
    topi[tid] = -1;        topi[tid + 256] = -1;
    __syncthreads();

    int ty = tid >> 4, tx = tid & 15;   // 16x16 threads, 4x4 microtile
    int rr = tid >> 3, kq = tid & 7;    // staging decomposition
    const float* xA = x + (b * T + t0) * D;

    float vmin = -INFINITY; int minp = 0;   // per-row top-8 state (tid<64 owns row tid)
    int nsub = ((t0 - c0) >> 6) + 1; if (nsub > 8) nsub = 8;

    for (int s = 0; s < nsub; ++s) {
        int j0 = c0 + (s << 6);
        const float* xB = x + (b * T + j0) * D;
        float acc[4][4];
        #pragma unroll
        for (int i = 0; i < 4; ++i)
            #pragma unroll
            for (int j = 0; j < 4; ++j) acc[i][j] = 0.f;

        for (int kc = 0; kc < D / 32; ++kc) {
            int k0 = kc * 32;
            __syncthreads();   // protect LDS (staging / S) from previous phase
            #pragma unroll
            for (int p = 0; p < 2; ++p) {
                int row = p * 32 + rr;
                float4 v = *(const float4*)(xA + row * D + k0 + (kq << 2));
                float4 u = *(const float4*)(xB + row * D + k0 + (kq << 2));
                int kk = kq << 2;
                As[(kk    ) * 68 + row] = v.x; As[(kk + 1) * 68 + row] = v.y;
                As[(kk + 2) * 68 + row] = v.z; As[(kk + 3) * 68 + row] = v.w;
                Bs[(kk    ) * 68 + row] = u.x; Bs[(kk + 1) * 68 + row] = u.y;
                Bs[(kk + 2) * 68 + row] = u.z; Bs[(kk + 3) * 68 + row] = u.w;
            }
            __syncthreads();
            #pragma unroll
            for (int kk = 0; kk < 32; ++kk) {
                float4 a  = *(const float4*)&As[kk * 68 + (ty << 2)];
                float4 bb = *(const float4*)&Bs[kk * 68 + (tx << 2)];
                acc[0][0] += a.x * bb.x; acc[0][1] += a.x * bb.y;
                acc[0][2] += a.x * bb.z; acc[0][3] += a.x * bb.w;
                acc[1][0] += a.y * bb.x; acc[1][1] += a.y * bb.y;
                acc[1][2] += a.y * bb.z; acc[1][3] += a.y * bb.w;
                acc[2][0] += a.z * bb.x; acc[2][1] += a.z * bb.y;
                acc[2][2] += a.z * bb.z; acc[2][3] += a.z * bb.w;
                acc[3][0] += a.w * bb.x; acc[3][1] += a.w * bb.y;
                acc[3][2] += a.w * bb.z; acc[3][3] += a.w * bb.w;
            }
        }
        __syncthreads();
        #pragma unroll
        for (int i = 0; i < 4; ++i)
            #pragma unroll
            for (int j = 0; j < 4; ++j)
                S[((ty << 2) + i) * 65 + (tx << 2) + j] = acc[i][j];
        __syncthreads();
        if (tid < 64) {                       // wave 0: merge 64 candidates per row
            int t = t0 + tid;
            int cmax = t - j0; if (cmax > 64) cmax = 64;   // causal j < t
            for (int c = 0; c < cmax; ++c) {
                float v = S[tid * 65 + c];
                if (v > vmin) {
                    topv[(tid << 3) + minp] = v; topi[(tid << 3) + minp] = j0 + c;
                    vmin = topv[tid << 3]; minp = 0;
                    #pragma unroll
                    for (int i = 1; i < 8; ++i) {
                        float tv = topv[(tid << 3) + i];
                        if (tv < vmin) { vmin = tv; minp = i; }
                    }
                }
            }
        }
        __syncthreads();
    }
    if (tid < 64) {
        int t = t0 + tid;
        int base = (b * T + t) * 64 + ((c0 >> 9) << 3);
        #pragma unroll
        for (int i = 0; i < 8; ++i) {
            pvals[base + i] = topv[(tid << 3) + i];
            pidx [base + i] = topi[(tid << 3) + i];
        }
    }
}

// ---------------- K3: merge chunk top-8s + attention + gelu epilogue ----------
// one wave per row; grid = B*T/4 blocks of 256
__global__ __launch_bounds__(256) void attn_kernel(const float* __restrict__ x,
        const float* __restrict__ q, const float* __restrict__ k,
        const float* __restrict__ meansum,
        const float* __restrict__ pvals, const int* __restrict__ pidx,
        const float* __restrict__ gain, const float* __restrict__ bias,
        const float* __restrict__ plm, const float* __restrict__ pls,
        float* __restrict__ out)
{
    int wav = threadIdx.x >> 6, lane = threadIdx.x & 63;
    int rid = (blockIdx.x << 2) + wav;       // global row b*T+t
    int b = rid >> 12, t = rid & (T - 1);

    float mix   = 1.f / (1.f + expf(-plm[0]));
    float scale = log1pf(expf(pls[0])) + 0.01f;

    int nc  = (t + 511) >> 9;                // ceil(t/512): valid chunks
    int nc8 = nc << 3;
    float cv = -INFINITY; int ci = -1;
    if (lane < nc8) { cv = pvals[(rid << 6) + lane]; ci = pidx[(rid << 6) + lane]; }

    float sv[8]; int si[8];
    #pragma unroll
    for (int i = 0; i < 8; ++i) {            // 8x wave argmax with deterministic ties
        float mv = cv; int mi = ci;
        #pragma unroll
        for (int off = 32; off >= 1; off >>= 1) {
            float ov = __shfl_xor(mv, off);
            int   oi = __shfl_xor(mi, off);
            if (ov > mv || (ov == mv && oi < mi)) { mv = ov; mi = oi; }
        }
        sv[i] = mv; si[i] = mi;
        if (cv == mv && ci == mi) cv = -INFINITY;
    }

    // scores: lanes 8i..8i+7 compute dot(q[t], k[sel_i]) (4 elems each, xor-reduce)
    int i8 = lane >> 3, e = lane & 7;
    bool v8 = sv[i8] > -1e37f;
    int g8 = v8 ? si[i8] : 0;
    float4 qv = *(const float4*)(q + rid * DH + (e << 2));
    float4 kv = *(const float4*)(k + ((b << 12) + g8) * DH + (e << 2));
    float p = qv.x * kv.x + qv.y * kv.y + qv.z * kv.z + qv.w * kv.w;
    p += __shfl_xor(p, 1); p += __shfl_xor(p, 2); p += __shfl_xor(p, 4);
    p *= 0.17677669529663687f;               // 1/sqrt(32)

    float sc[8];
    #pragma unroll
    for (int i = 0; i < 8; ++i) sc[i] = __shfl(p, i << 3);

    float m = -INFINITY; int cnt = 0;
    #pragma unroll
    for (int i = 0; i < 8; ++i)
        if (sv[i] > -1e37f) { ++cnt; if (sc[i] > m) m = sc[i]; }

    float w[8]; float Z = 0.f; int gsel[8];
    #pragma unroll
    for (int i = 0; i < 8; ++i) {
        bool val = sv[i] > -1e37f;
        w[i] = val ? expf(sc[i] - m) : 0.f;
        Z += w[i];
        gsel[i] = val ? ((b << 12) + si[i]) : (b << 12);
    }
    float invZ = (cnt > 0) ? 1.f / Z : 0.f;
    #pragma unroll
    for (int i = 0; i < 8; ++i) w[i] *= invZ;

    const float* xt = x + rid * D;
    float* ot = out + rid * D;
    const float onemix = 1.f - mix;

    if (cnt == 0) {                          // t==0: uniform attention over ALL T
        const float* ms = meansum + (b << 10);
        for (int u = 0; u < 16; ++u) {
            int d = lane + (u << 6);
            float msg = ms[d] * (1.f / (float)T);
            float z = (mix * xt[d] + onemix * msg) * gain[d] + bias[d];
            ot[d] = 0.5f * z * (1.f + erff(z * 0.70710678118654752f)) * scale;
        }
    } else {
        const float* r0 = x + gsel[0] * D; const float* r1 = x + gsel[1] * D;
        const float* r2 = x + gsel[2] * D; const float* r3 = x + gsel[3] * D;
        const float* r4 = x + gsel[4] * D; const float* r5 = x + gsel[5] * D;
        const float* r6 = x + gsel[6] * D; const float* r7 = x + gsel[7] * D;
        for (int u = 0; u < 16; ++u) {
            int d = lane + (u << 6);
            float msg = w[0] * r0[d] + w[1] * r1[d] + w[2] * r2[d] + w[3] * r3[d]
                      + w[4] * r4[d] + w[5] * r5[d] + w[6] * r6[d] + w[7] * r7[d];
            float z = (mix * xt[d] + onemix * msg) * gain[d] + bias[d];
            ot[d] = 0.5f * z * (1.f + erff(z * 0.70710678118654752f)) * scale;
        }
    }
}

extern "C" void kernel_launch(void* const* d_in, const int* in_sizes, int n_in,
                              void* d_out, int out_size, void* d_ws, size_t ws_size,
                              hipStream_t stream)
{
    const float* x    = (const float*)d_in[0];
    const float* Wq   = (const float*)d_in[1];
    const float* Wk   = (const float*)d_in[2];
    const float* gain = (const float*)d_in[3];
    const float* bias = (const float*)d_in[4];
    const float* plm  = (const float*)d_in[5];
    const float* pls  = (const float*)d_in[6];
    float* out = (float*)d_out;

    float* ws      = (float*)d_ws;
    float* q       = ws;                 // B*T*32 = 262144 floats
    float* k       = ws + 262144;        // 262144 floats
    float* meansum = ws + 524288;        // B*1024 = 2048 floats
    float* pvals   = ws + 526336;        // B*T*NC*8 = 524288 floats
    int*   pidx    = (int*)(ws + 1050624); // 524288 ints
    // total ws use: ~6.3 MB

    hipMemsetAsync(meansum, 0, 2048 * sizeof(float), stream);
    mean_kernel<<<128, 256, 0, stream>>>(x, meansum);
    qk_kernel<<<B * T / 4, 256, 0, stream>>>(x, Wq, Wk, q, k);
    topk_kernel<<<B * NT * NC, 256, 0, stream>>>(x, pvals, pidx);
    attn_kernel<<<B * T / 4, 256, 0, stream>>>(x, q, k, meansum, pvals, pidx,
                                               gain, bias, plm, pls, out);
}

// Round 3
// 659.653 us; speedup vs baseline: 2.0923x; 2.0923x over previous
//
#include <hip/hip_runtime.h>
#include <math.h>

#define B 2
#define T 4096
#define D 1024
#define DH 32
#define TNB 32        // 128-row tiles per batch
#define NBLK 528      // TNB*(TNB+1)/2 causal tile pairs
#define NK 12         // per-chunk candidates kept (safety margin over 8)
#define CPR (32*NK)   // candidates per row = 384

typedef __bf16 bf16x8 __attribute__((ext_vector_type(8)));
typedef float f32x4 __attribute__((ext_vector_type(4)));

// ---------------- K_conv: x -> (hi, lo) bf16 split ----------------
__global__ __launch_bounds__(256) void conv_kernel(const float* __restrict__ x,
        __bf16* __restrict__ xhi, __bf16* __restrict__ xlo)
{
    int i = (blockIdx.x * 256 + threadIdx.x) << 3;     // 8 floats/thread
    float4 a = *(const float4*)(x + i);
    float4 c = *(const float4*)(x + i + 4);
    float av[8] = {a.x, a.y, a.z, a.w, c.x, c.y, c.z, c.w};
    __bf16 h[8], l[8];
    #pragma unroll
    for (int j = 0; j < 8; ++j) {
        h[j] = (__bf16)av[j];
        l[j] = (__bf16)(av[j] - (float)h[j]);
    }
    *(float4*)(xhi + i) = *(float4*)h;
    *(float4*)(xlo + i) = *(float4*)l;
}

// ---------------- K0: per-batch column sums (for the t=0 row) ----------------
__global__ void mean_kernel(const float* __restrict__ x, float* __restrict__ meansum)
{
    int gid  = blockIdx.x;           // B * 4 dblk * 16 tch = 128 blocks
    int b    = gid >> 6;
    int rem  = gid & 63;
    int dblk = rem >> 4;
    int tch  = rem & 15;
    int d = dblk * 256 + threadIdx.x;
    const float* xp = x + (b * T + tch * 256) * D + d;
    float s = 0.f;
    #pragma unroll 8
    for (int it = 0; it < 256; ++it) s += xp[it * D];
    atomicAdd(&meansum[(b << 10) + d], s);
}

// ---------------- K1: q/k projections ----------------
__global__ __launch_bounds__(256) void qk_kernel(const float* __restrict__ x,
        const float* __restrict__ Wq, const float* __restrict__ Wk,
        float* __restrict__ qo, float* __restrict__ ko)
{
    __shared__ __align__(16) float xs[4 * D];
    int tid = threadIdx.x;
    int row0 = blockIdx.x * 4;
    const float4* src = (const float4*)(x + row0 * D);
    float4* dst = (float4*)xs;
    #pragma unroll
    for (int p = 0; p < 4; ++p) dst[p * 256 + tid] = src[p * 256 + tid];
    __syncthreads();
    int w = tid >> 6, lane = tid & 63;
    int r = row0 + w;
    const float* W = (lane < DH) ? (Wq + lane * D) : (Wk + (lane - DH) * D);
    const float4* W4 = (const float4*)W;
    const float4* xr = (const float4*)(xs + w * D);
    float s = 0.f;
    #pragma unroll 4
    for (int d4 = 0; d4 < D / 4; ++d4) {
        float4 a = xr[d4]; float4 ww = W4[d4];
        s += a.x * ww.x + a.y * ww.y + a.z * ww.z + a.w * ww.w;
    }
    if (lane < DH) qo[r * DH + lane] = s;
    else           ko[r * DH + (lane - DH)] = s;
}

// ---------------- K2: split-bf16 MFMA sim GEMM + per-row top-12 per 128-col chunk --
__global__ __launch_bounds__(256, 2) void topk_mfma_kernel(
        const __bf16* __restrict__ xhi, const __bf16* __restrict__ xlo,
        float* __restrict__ pvals, int* __restrict__ pidx)
{
    __shared__ __align__(16) float Sbuf[128 * 129];    // 66048 B
    __bf16* stg = (__bf16*)Sbuf;
    __bf16* sAhi = stg;
    __bf16* sAlo = stg + 5120;
    __bf16* sBhi = stg + 10240;
    __bf16* sBlo = stg + 15360;

    int tid = threadIdx.x;
    int b = blockIdx.x / NBLK;
    int l = blockIdx.x - b * NBLK;
    int rt = (int)((sqrtf(8.f * l + 1.f) - 1.f) * 0.5f);
    while ((rt + 1) * (rt + 2) / 2 <= l) ++rt;
    while (rt * (rt + 1) / 2 > l) --rt;
    int ct = l - rt * (rt + 1) / 2;
    int r0 = rt << 7, c0 = ct << 7;
    int base = b * T;

    int w = tid >> 6, lane = tid & 63;
    int wr = (w >> 1) << 6, wc = (w & 1) << 6;
    bool active = !(rt == ct && w == 1);   // diag block, fully non-causal quadrant

    int srow = tid >> 2, sq = tid & 3;     // staging: thread -> (row, 16B chunk)
    int fr = lane & 15, fq = lane >> 4;    // fragment: row-in-tile, k-quad

    const __bf16* gAh = xhi + (base + r0) * D;
    const __bf16* gAl = xlo + (base + r0) * D;
    const __bf16* gBh = xhi + (base + c0) * D;
    const __bf16* gBl = xlo + (base + c0) * D;

    f32x4 acc[4][4];
    #pragma unroll
    for (int i = 0; i < 4; ++i)
        #pragma unroll
        for (int j = 0; j < 4; ++j) acc[i][j] = (f32x4){0.f, 0.f, 0.f, 0.f};

    int o0 = srow * D + sq * 8;
    int o1 = o0 + 64 * D;
    float4 pf0 = *(const float4*)(gAh + o0);
    float4 pf1 = *(const float4*)(gAh + o1);
    float4 pf2 = *(const float4*)(gAl + o0);
    float4 pf3 = *(const float4*)(gAl + o1);
    float4 pf4 = *(const float4*)(gBh + o0);
    float4 pf5 = *(const float4*)(gBh + o1);
    float4 pf6 = *(const float4*)(gBl + o0);
    float4 pf7 = *(const float4*)(gBl + o1);

    int s0 = srow * 40 + sq * 8;
    int s1 = s0 + 64 * 40;

    for (int kc = 0; kc < 32; ++kc) {
        __syncthreads();
        *(float4*)(sAhi + s0) = pf0;  *(float4*)(sAhi + s1) = pf1;
        *(float4*)(sAlo + s0) = pf2;  *(float4*)(sAlo + s1) = pf3;
        *(float4*)(sBhi + s0) = pf4;  *(float4*)(sBhi + s1) = pf5;
        *(float4*)(sBlo + s0) = pf6;  *(float4*)(sBlo + s1) = pf7;
        if (kc + 1 < 32) {
            int k0 = (kc + 1) << 5;
            int n0 = srow * D + k0 + sq * 8;
            int n1 = n0 + 64 * D;
            pf0 = *(const float4*)(gAh + n0);
            pf1 = *(const float4*)(gAh + n1);
            pf2 = *(const float4*)(gAl + n0);
            pf3 = *(const float4*)(gAl + n1);
            pf4 = *(const float4*)(gBh + n0);
            pf5 = *(const float4*)(gBh + n1);
            pf6 = *(const float4*)(gBl + n0);
            pf7 = *(const float4*)(gBl + n1);
        }
        __syncthreads();
        if (active) {
            bf16x8 ah[4], al[4], bh[4], bl[4];
            #pragma unroll
            for (int i = 0; i < 4; ++i) {
                int ar = wr + i * 16 + fr;
                ah[i] = *(const bf16x8*)(sAhi + ar * 40 + fq * 8);
                al[i] = *(const bf16x8*)(sAlo + ar * 40 + fq * 8);
                int bc = wc + i * 16 + fr;
                bh[i] = *(const bf16x8*)(sBhi + bc * 40 + fq * 8);
                bl[i] = *(const bf16x8*)(sBlo + bc * 40 + fq * 8);
            }
            #pragma unroll
            for (int i = 0; i < 4; ++i)
                #pragma unroll
                for (int j = 0; j < 4; ++j) {
                    acc[i][j] = __builtin_amdgcn_mfma_f32_16x16x32_bf16(ah[i], bh[j], acc[i][j], 0, 0, 0);
                    acc[i][j] = __builtin_amdgcn_mfma_f32_16x16x32_bf16(ah[i], bl[j], acc[i][j], 0, 0, 0);
                    acc[i][j] = __builtin_amdgcn_mfma_f32_16x16x32_bf16(al[i], bh[j], acc[i][j], 0, 0, 0);
                }
        }
    }
    __syncthreads();
    {   // write S: C layout col=lane&15, row=(lane>>4)*4+reg
        int cr = fq << 2, cc = fr;
        #pragma unroll
        for (int i = 0; i < 4; ++i)
            #pragma unroll
            for (int j = 0; j < 4; ++j) {
                float* sp = Sbuf + (wr + i * 16 + cr) * 129 + wc + j * 16 + cc;
                sp[0]       = acc[i][j][0];
                sp[129]     = acc[i][j][1];
                sp[2 * 129] = acc[i][j][2];
                sp[3 * 129] = acc[i][j][3];
            }
    }
    __syncthreads();
    if (tid < 128) {                       // per-row top-12 over this 128-col chunk
        int gt = r0 + tid;
        int cmax = gt - c0;
        if (cmax > 128) cmax = 128;
        if (cmax < 0) cmax = 0;
        float tv[NK]; int ti[NK];
        #pragma unroll
        for (int i = 0; i < NK; ++i) { tv[i] = -INFINITY; ti[i] = -1; }
        float vmin = -INFINITY; int minp = 0;
        const float* Srow = Sbuf + tid * 129;
        for (int c = 0; c < cmax; ++c) {
            float v = Srow[c];
            if (v > vmin) {
                tv[minp] = v; ti[minp] = c0 + c;
                vmin = tv[0]; minp = 0;
                #pragma unroll
                for (int i = 1; i < NK; ++i)
                    if (tv[i] < vmin) { vmin = tv[i]; minp = i; }
            }
        }
        int ob = (base + gt) * CPR + ct * NK;
        #pragma unroll
        for (int i = 0; i < NK; ++i) { pvals[ob + i] = tv[i]; pidx[ob + i] = ti[i]; }
    }
}

// ---------------- K3: merge -> approx top-12 -> EXACT fp32 re-rank -> top-8
//                  -> attention + gelu epilogue. One wave per row. -------------
__global__ __launch_bounds__(256) void attn_kernel(const float* __restrict__ x,
        const float* __restrict__ q, const float* __restrict__ k,
        const float* __restrict__ meansum,
        const float* __restrict__ pvals, const int* __restrict__ pidx,
        const float* __restrict__ gain, const float* __restrict__ bias,
        const float* __restrict__ plm, const float* __restrict__ pls,
        float* __restrict__ out)
{
    int wav = threadIdx.x >> 6, lane = threadIdx.x & 63;
    int rid = (blockIdx.x << 2) + wav;       // global row b*T+t
    int b = rid >> 12, t = rid & (T - 1);

    float mix   = 1.f / (1.f + expf(-plm[0]));
    float scale = log1pf(expf(pls[0])) + 0.01f;

    int ncand = NK * ((t + 127) >> 7);       // NK * ceil(t/128)
    float cv[6]; int ci[6];
    #pragma unroll
    for (int u = 0; u < 6; ++u) {
        int cid = lane + (u << 6);
        bool val = cid < ncand;
        cv[u] = val ? pvals[rid * CPR + cid] : -INFINITY;
        ci[u] = val ? pidx[rid * CPR + cid] : -1;
    }

    // merge: approx top-12 across all chunks
    float sv[NK]; int si[NK];
    #pragma unroll
    for (int i = 0; i < NK; ++i) {
        float mv = cv[0]; int mi = ci[0];
        #pragma unroll
        for (int u = 1; u < 6; ++u)
            if (cv[u] > mv || (cv[u] == mv && ci[u] < mi)) { mv = cv[u]; mi = ci[u]; }
        #pragma unroll
        for (int off = 32; off >= 1; off >>= 1) {
            float ov = __shfl_xor(mv, off);
            int   oi = __shfl_xor(mi, off);
            if (ov > mv || (ov == mv && oi < mi)) { mv = ov; mi = oi; }
        }
        sv[i] = mv; si[i] = mi;
        #pragma unroll
        for (int u = 0; u < 6; ++u)
            if (cv[u] == mv && ci[u] == mi) cv[u] = -INFINITY;
    }

    // exact fp32 re-rank of the 12 candidates
    const float* xt = x + rid * D;
    float4 xt4[4];
    #pragma unroll
    for (int c = 0; c < 4; ++c)
        xt4[c] = *(const float4*)(xt + (c << 8) + (lane << 2));
    float ex[NK];
    #pragma unroll
    for (int i = 0; i < NK; ++i) {
        bool val = si[i] >= 0;
        const float* xj = x + ((size_t)((b << 12) + (val ? si[i] : 0))) * D;
        float s = 0.f;
        #pragma unroll
        for (int c = 0; c < 4; ++c) {
            float4 v = *(const float4*)(xj + (c << 8) + (lane << 2));
            s += xt4[c].x * v.x + xt4[c].y * v.y + xt4[c].z * v.z + xt4[c].w * v.w;
        }
        #pragma unroll
        for (int off = 32; off >= 1; off >>= 1) s += __shfl_xor(s, off);
        ex[i] = val ? s : -INFINITY;
    }

    // exact top-8 (tie-break: lower index)
    float bv[8]; int bi[8];
    #pragma unroll
    for (int r = 0; r < 8; ++r) {
        int mp = 0;
        #pragma unroll
        for (int i = 1; i < NK; ++i) {
            bool better = (ex[i] > ex[mp]) ||
                          (ex[i] == ex[mp] && si[i] >= 0 &&
                           (si[mp] < 0 || si[i] < si[mp]));
            if (better) mp = i;
        }
        bv[r] = ex[mp]; bi[r] = si[mp];
        ex[mp] = -INFINITY;
    }

    // scores: lanes 8i..8i+7 compute dot(q[t], k[sel_i])
    int i8 = lane >> 3, e = lane & 7;
    bool v8 = bv[i8] > -1e37f;
    int g8 = v8 ? bi[i8] : 0;
    float4 qv = *(const float4*)(q + rid * DH + (e << 2));
    float4 kv = *(const float4*)(k + ((b << 12) + g8) * DH + (e << 2));
    float p = qv.x * kv.x + qv.y * kv.y + qv.z * kv.z + qv.w * kv.w;
    p += __shfl_xor(p, 1); p += __shfl_xor(p, 2); p += __shfl_xor(p, 4);
    p *= 0.17677669529663687f;               // 1/sqrt(32)

    float sc[8];
    #pragma unroll
    for (int i = 0; i < 8; ++i) sc[i] = __shfl(p, i << 3);

    float m = -INFINITY; int cnt = 0;
    #pragma unroll
    for (int i = 0; i < 8; ++i)
        if (bv[i] > -1e37f) { ++cnt; if (sc[i] > m) m = sc[i]; }

    float wgt[8]; float Z = 0.f; int gsel[8];
    #pragma unroll
    for (int i = 0; i < 8; ++i) {
        bool val = bv[i] > -1e37f;
        wgt[i] = val ? expf(sc[i] - m) : 0.f;
        Z += wgt[i];
        gsel[i] = val ? ((b << 12) + bi[i]) : (b << 12);
    }
    float invZ = (cnt > 0) ? 1.f / Z : 0.f;
    #pragma unroll
    for (int i = 0; i < 8; ++i) wgt[i] *= invZ;

    float* ot = out + rid * D;
    const float onemix = 1.f - mix;

    if (cnt == 0) {                          // t==0: uniform attention over ALL T
        const float* ms = meansum + (b << 10);
        for (int u = 0; u < 16; ++u) {
            int d = lane + (u << 6);
            float msg = ms[d] * (1.f / (float)T);
            float z = (mix * xt[d] + onemix * msg) * gain[d] + bias[d];
            ot[d] = 0.5f * z * (1.f + erff(z * 0.70710678118654752f)) * scale;
        }
    } else {
        const float* r0 = x + gsel[0] * D; const float* r1 = x + gsel[1] * D;
        const float* r2 = x + gsel[2] * D; const float* r3 = x + gsel[3] * D;
        const float* r4 = x + gsel[4] * D; const float* r5 = x + gsel[5] * D;
        const float* r6 = x + gsel[6] * D; const float* r7 = x + gsel[7] * D;
        for (int u = 0; u < 16; ++u) {
            int d = lane + (u << 6);
            float msg = wgt[0] * r0[d] + wgt[1] * r1[d] + wgt[2] * r2[d] + wgt[3] * r3[d]
                      + wgt[4] * r4[d] + wgt[5] * r5[d] + wgt[6] * r6[d] + wgt[7] * r7[d];
            float z = (mix * xt[d] + onemix * msg) * gain[d] + bias[d];
            ot[d] = 0.5f * z * (1.f + erff(z * 0.70710678118654752f)) * scale;
        }
    }
}

extern "C" void kernel_launch(void* const* d_in, const int* in_sizes, int n_in,
                              void* d_out, int out_size, void* d_ws, size_t ws_size,
                              hipStream_t stream)
{
    const float* x    = (const float*)d_in[0];
    const float* Wq   = (const float*)d_in[1];
    const float* Wk   = (const float*)d_in[2];
    const float* gain = (const float*)d_in[3];
    const float* bias = (const float*)d_in[4];
    const float* plm  = (const float*)d_in[5];
    const float* pls  = (const float*)d_in[6];
    float* out = (float*)d_out;

    float* ws      = (float*)d_ws;
    float* q       = ws;                       // 262144
    float* k       = ws + 262144;              // 262144
    float* meansum = ws + 524288;              // 2048
    float* pvals   = ws + 526336;              // B*T*CPR = 3145728
    int*   pidx    = (int*)(ws + 3672064);     // 3145728
    __bf16* xhi    = (__bf16*)(ws + 6817792);  // B*T*D bf16
    __bf16* xlo    = xhi + (size_t)B * T * D;
    // total ws use: ~61 MB

    hipMemsetAsync(meansum, 0, 2048 * sizeof(float), stream);
    conv_kernel<<<B * T * D / 2048, 256, 0, stream>>>(x, xhi, xlo);
    mean_kernel<<<128, 256, 0, stream>>>(x, meansum);
    qk_kernel<<<B * T / 4, 256, 0, stream>>>(x, Wq, Wk, q, k);
    topk_mfma_kernel<<<B * NBLK, 256, 0, stream>>>(xhi, xlo, pvals, pidx);
    attn_kernel<<<B * T / 4, 256, 0, stream>>>(x, q, k, meansum, pvals, pidx,
                                               gain, bias, plm, pls, out);
}

// Round 4
// 554.752 us; speedup vs baseline: 2.4879x; 1.1891x over previous
//
#include <hip/hip_runtime.h>
#include <math.h>

#define B 2
#define T 4096
#define D 1024
#define DH 32
#define TNB 32        // 128-row tiles per batch
#define NBLK 528      // TNB*(TNB+1)/2 causal tile pairs
#define NK 12         // per-chunk candidates kept (safety margin over 8)
#define CPR (32*NK)   // candidates per row = 384

typedef __bf16 bf16x8 __attribute__((ext_vector_type(8)));
typedef float f32x4 __attribute__((ext_vector_type(4)));

// ---------------- K_conv: src -> (hi, lo) bf16 split (2048 elems/block) -------
__global__ __launch_bounds__(256) void conv_kernel(const float* __restrict__ x,
        __bf16* __restrict__ xhi, __bf16* __restrict__ xlo)
{
    int i = (blockIdx.x * 256 + threadIdx.x) << 3;     // 8 floats/thread
    float4 a = *(const float4*)(x + i);
    float4 c = *(const float4*)(x + i + 4);
    float av[8] = {a.x, a.y, a.z, a.w, c.x, c.y, c.z, c.w};
    __bf16 h[8], l[8];
    #pragma unroll
    for (int j = 0; j < 8; ++j) {
        h[j] = (__bf16)av[j];
        l[j] = (__bf16)(av[j] - (float)h[j]);
    }
    *(float4*)(xhi + i) = *(float4*)h;
    *(float4*)(xlo + i) = *(float4*)l;
}

// ---------------- K0: per-batch column sums (for the t=0 row) ----------------
__global__ void mean_kernel(const float* __restrict__ x, float* __restrict__ meansum)
{
    int gid  = blockIdx.x;           // B * 4 dblk * 16 tch = 128 blocks
    int b    = gid >> 6;
    int rem  = gid & 63;
    int dblk = rem >> 4;
    int tch  = rem & 15;
    int d = dblk * 256 + threadIdx.x;
    const float* xp = x + (b * T + tch * 256) * D + d;
    float s = 0.f;
    #pragma unroll 8
    for (int it = 0; it < 256; ++it) s += xp[it * D];
    atomicAdd(&meansum[(b << 10) + d], s);
}

// ---------------- K1: q/k projection as split-bf16 MFMA GEMM -----------------
// M=8192 (128 rows/block, 64 blocks), N=64 (Wq||Wk), K=1024.
// Wave w owns rows [w*32, w*32+32): 2 m-tiles x 4 n-tiles of 16x16x32.
__global__ __launch_bounds__(256) void qk_mfma_kernel(
        const __bf16* __restrict__ xhi, const __bf16* __restrict__ xlo,
        const __bf16* __restrict__ Whi, const __bf16* __restrict__ Wlo,
        float* __restrict__ qo, float* __restrict__ ko)
{
    __shared__ __align__(16) __bf16 stg[15360];
    __bf16* sAhi = stg;            // 128 x 40
    __bf16* sAlo = stg + 5120;
    __bf16* sBhi = stg + 10240;    // 64 x 40
    __bf16* sBlo = stg + 12800;

    int tid = threadIdx.x;
    int m0 = blockIdx.x << 7;
    int w = tid >> 6, lane = tid & 63;
    int fr = lane & 15, fq = lane >> 4;

    int arow = tid >> 1, ah = tid & 1;      // A staging: 2 chunks of 16 bf16
    int brow = tid >> 2, bq = tid & 3;      // B staging: 4 chunks of 8 bf16

    const __bf16* gAh = xhi + (size_t)(m0 + arow) * D + ah * 16;
    const __bf16* gAl = xlo + (size_t)(m0 + arow) * D + ah * 16;
    const __bf16* gBh = Whi + brow * D + bq * 8;
    const __bf16* gBl = Wlo + brow * D + bq * 8;

    f32x4 acc[2][4];
    #pragma unroll
    for (int i = 0; i < 2; ++i)
        #pragma unroll
        for (int j = 0; j < 4; ++j) acc[i][j] = (f32x4){0.f, 0.f, 0.f, 0.f};

    float4 a0 = *(const float4*)(gAh);
    float4 a1 = *(const float4*)(gAh + 8);
    float4 a2 = *(const float4*)(gAl);
    float4 a3 = *(const float4*)(gAl + 8);
    float4 b0 = *(const float4*)(gBh);
    float4 b1 = *(const float4*)(gBl);

    int sa = arow * 40 + ah * 16;
    int sb = brow * 40 + bq * 8;

    for (int kc = 0; kc < 32; ++kc) {
        __syncthreads();
        *(float4*)(sAhi + sa) = a0;  *(float4*)(sAhi + sa + 8) = a1;
        *(float4*)(sAlo + sa) = a2;  *(float4*)(sAlo + sa + 8) = a3;
        *(float4*)(sBhi + sb) = b0;  *(float4*)(sBlo + sb) = b1;
        if (kc + 1 < 32) {
            int k0 = (kc + 1) << 5;
            a0 = *(const float4*)(gAh + k0);
            a1 = *(const float4*)(gAh + k0 + 8);
            a2 = *(const float4*)(gAl + k0);
            a3 = *(const float4*)(gAl + k0 + 8);
            b0 = *(const float4*)(gBh + k0);
            b1 = *(const float4*)(gBl + k0);
        }
        __syncthreads();
        bf16x8 fah[2], fal[2], fbh[4], fbl[4];
        #pragma unroll
        for (int i = 0; i < 2; ++i) {
            int r = (w << 5) + i * 16 + fr;
            fah[i] = *(const bf16x8*)(sAhi + r * 40 + fq * 8);
            fal[i] = *(const bf16x8*)(sAlo + r * 40 + fq * 8);
        }
        #pragma unroll
        for (int j = 0; j < 4; ++j) {
            int r = j * 16 + fr;
            fbh[j] = *(const bf16x8*)(sBhi + r * 40 + fq * 8);
            fbl[j] = *(const bf16x8*)(sBlo + r * 40 + fq * 8);
        }
        #pragma unroll
        for (int i = 0; i < 2; ++i)
            #pragma unroll
            for (int j = 0; j < 4; ++j) {
                acc[i][j] = __builtin_amdgcn_mfma_f32_16x16x32_bf16(fah[i], fbh[j], acc[i][j], 0, 0, 0);
                acc[i][j] = __builtin_amdgcn_mfma_f32_16x16x32_bf16(fah[i], fbl[j], acc[i][j], 0, 0, 0);
                acc[i][j] = __builtin_amdgcn_mfma_f32_16x16x32_bf16(fal[i], fbh[j], acc[i][j], 0, 0, 0);
            }
    }
    // writeout: C layout col=lane&15, row=fq*4+reg
    #pragma unroll
    for (int i = 0; i < 2; ++i) {
        int grow0 = m0 + (w << 5) + i * 16 + (fq << 2);
        #pragma unroll
        for (int j = 0; j < 4; ++j) {
            int gn = j * 16 + fr;
            float* dst = (gn < 32) ? (qo + grow0 * DH + gn)
                                   : (ko + grow0 * DH + gn - 32);
            dst[0]      = acc[i][j][0];
            dst[DH]     = acc[i][j][1];
            dst[2 * DH] = acc[i][j][2];
            dst[3 * DH] = acc[i][j][3];
        }
    }
}

// ---------------- K2: split-bf16 MFMA sim GEMM + per-row top-12 per 128-col chunk --
__global__ __launch_bounds__(256, 2) void topk_mfma_kernel(
        const __bf16* __restrict__ xhi, const __bf16* __restrict__ xlo,
        float* __restrict__ pvals, int* __restrict__ pidx)
{
    __shared__ __align__(16) float Sbuf[128 * 129];    // 66048 B
    __bf16* stg = (__bf16*)Sbuf;
    __bf16* sAhi = stg;
    __bf16* sAlo = stg + 5120;
    __bf16* sBhi = stg + 10240;
    __bf16* sBlo = stg + 15360;

    int tid = threadIdx.x;
    int b = blockIdx.x / NBLK;
    int l = blockIdx.x - b * NBLK;
    int rt = (int)((sqrtf(8.f * l + 1.f) - 1.f) * 0.5f);
    while ((rt + 1) * (rt + 2) / 2 <= l) ++rt;
    while (rt * (rt + 1) / 2 > l) --rt;
    int ct = l - rt * (rt + 1) / 2;
    int r0 = rt << 7, c0 = ct << 7;
    int base = b * T;

    int w = tid >> 6, lane = tid & 63;
    int wr = (w >> 1) << 6, wc = (w & 1) << 6;
    bool active = !(rt == ct && w == 1);   // diag block, fully non-causal quadrant

    int srow = tid >> 2, sq = tid & 3;     // staging: thread -> (row, 16B chunk)
    int fr = lane & 15, fq = lane >> 4;    // fragment: row-in-tile, k-quad

    const __bf16* gAh = xhi + (base + r0) * D;
    const __bf16* gAl = xlo + (base + r0) * D;
    const __bf16* gBh = xhi + (base + c0) * D;
    const __bf16* gBl = xlo + (base + c0) * D;

    f32x4 acc[4][4];
    #pragma unroll
    for (int i = 0; i < 4; ++i)
        #pragma unroll
        for (int j = 0; j < 4; ++j) acc[i][j] = (f32x4){0.f, 0.f, 0.f, 0.f};

    int o0 = srow * D + sq * 8;
    int o1 = o0 + 64 * D;
    float4 pf0 = *(const float4*)(gAh + o0);
    float4 pf1 = *(const float4*)(gAh + o1);
    float4 pf2 = *(const float4*)(gAl + o0);
    float4 pf3 = *(const float4*)(gAl + o1);
    float4 pf4 = *(const float4*)(gBh + o0);
    float4 pf5 = *(const float4*)(gBh + o1);
    float4 pf6 = *(const float4*)(gBl + o0);
    float4 pf7 = *(const float4*)(gBl + o1);

    int s0 = srow * 40 + sq * 8;
    int s1 = s0 + 64 * 40;

    for (int kc = 0; kc < 32; ++kc) {
        __syncthreads();
        *(float4*)(sAhi + s0) = pf0;  *(float4*)(sAhi + s1) = pf1;
        *(float4*)(sAlo + s0) = pf2;  *(float4*)(sAlo + s1) = pf3;
        *(float4*)(sBhi + s0) = pf4;  *(float4*)(sBhi + s1) = pf5;
        *(float4*)(sBlo + s0) = pf6;  *(float4*)(sBlo + s1) = pf7;
        if (kc + 1 < 32) {
            int k0 = (kc + 1) << 5;
            int n0 = srow * D + k0 + sq * 8;
            int n1 = n0 + 64 * D;
            pf0 = *(const float4*)(gAh + n0);
            pf1 = *(const float4*)(gAh + n1);
            pf2 = *(const float4*)(gAl + n0);
            pf3 = *(const float4*)(gAl + n1);
            pf4 = *(const float4*)(gBh + n0);
            pf5 = *(const float4*)(gBh + n1);
            pf6 = *(const float4*)(gBl + n0);
            pf7 = *(const float4*)(gBl + n1);
        }
        __syncthreads();
        if (active) {
            bf16x8 ah[4], al[4], bh[4], bl[4];
            #pragma unroll
            for (int i = 0; i < 4; ++i) {
                int ar = wr + i * 16 + fr;
                ah[i] = *(const bf16x8*)(sAhi + ar * 40 + fq * 8);
                al[i] = *(const bf16x8*)(sAlo + ar * 40 + fq * 8);
                int bc = wc + i * 16 + fr;
                bh[i] = *(const bf16x8*)(sBhi + bc * 40 + fq * 8);
                bl[i] = *(const bf16x8*)(sBlo + bc * 40 + fq * 8);
            }
            #pragma unroll
            for (int i = 0; i < 4; ++i)
                #pragma unroll
                for (int j = 0; j < 4; ++j) {
                    acc[i][j] = __builtin_amdgcn_mfma_f32_16x16x32_bf16(ah[i], bh[j], acc[i][j], 0, 0, 0);
                    acc[i][j] = __builtin_amdgcn_mfma_f32_16x16x32_bf16(ah[i], bl[j], acc[i][j], 0, 0, 0);
                    acc[i][j] = __builtin_amdgcn_mfma_f32_16x16x32_bf16(al[i], bh[j], acc[i][j], 0, 0, 0);
                }
        }
    }
    __syncthreads();
    {   // write S: C layout col=lane&15, row=(lane>>4)*4+reg
        int cr = fq << 2, cc = fr;
        #pragma unroll
        for (int i = 0; i < 4; ++i)
            #pragma unroll
            for (int j = 0; j < 4; ++j) {
                float* sp = Sbuf + (wr + i * 16 + cr) * 129 + wc + j * 16 + cc;
                sp[0]       = acc[i][j][0];
                sp[129]     = acc[i][j][1];
                sp[2 * 129] = acc[i][j][2];
                sp[3 * 129] = acc[i][j][3];
            }
    }
    __syncthreads();
    if (tid < 128) {                       // per-row top-12 over this 128-col chunk
        int gt = r0 + tid;
        int cmax = gt - c0;
        if (cmax > 128) cmax = 128;
        if (cmax < 0) cmax = 0;
        float tv[NK]; int ti[NK];
        #pragma unroll
        for (int i = 0; i < NK; ++i) { tv[i] = -INFINITY; ti[i] = -1; }
        float vmin = -INFINITY; int minp = 0;
        const float* Srow = Sbuf + tid * 129;
        for (int c = 0; c < cmax; ++c) {
            float v = Srow[c];
            if (v > vmin) {
                tv[minp] = v; ti[minp] = c0 + c;
                vmin = tv[0]; minp = 0;
                #pragma unroll
                for (int i = 1; i < NK; ++i)
                    if (tv[i] < vmin) { vmin = tv[i]; minp = i; }
            }
        }
        int ob = (base + gt) * CPR + ct * NK;
        #pragma unroll
        for (int i = 0; i < NK; ++i) { pvals[ob + i] = tv[i]; pidx[ob + i] = ti[i]; }
    }
}

// ---------------- K3: merge -> approx top-12 -> EXACT fp32 re-rank -> top-8
//                  -> attention + gelu epilogue. One wave per row. -------------
__global__ __launch_bounds__(256) void attn_kernel(const float* __restrict__ x,
        const float* __restrict__ q, const float* __restrict__ k,
        const float* __restrict__ meansum,
        const float* __restrict__ pvals, const int* __restrict__ pidx,
        const float* __restrict__ gain, const float* __restrict__ bias,
        const float* __restrict__ plm, const float* __restrict__ pls,
        float* __restrict__ out)
{
    int wav = threadIdx.x >> 6, lane = threadIdx.x & 63;
    int rid = (blockIdx.x << 2) + wav;       // global row b*T+t
    int b = rid >> 12, t = rid & (T - 1);

    float mix   = 1.f / (1.f + expf(-plm[0]));
    float scale = log1pf(expf(pls[0])) + 0.01f;

    int ncand = NK * ((t + 127) >> 7);       // NK * ceil(t/128)
    float cv[6]; int ci[6];
    #pragma unroll
    for (int u = 0; u < 6; ++u) {
        int cid = lane + (u << 6);
        bool val = cid < ncand;
        cv[u] = val ? pvals[rid * CPR + cid] : -INFINITY;
        ci[u] = val ? pidx[rid * CPR + cid] : -1;
    }

    // merge: approx top-12 across all chunks
    float sv[NK]; int si[NK];
    #pragma unroll
    for (int i = 0; i < NK; ++i) {
        float mv = cv[0]; int mi = ci[0];
        #pragma unroll
        for (int u = 1; u < 6; ++u)
            if (cv[u] > mv || (cv[u] == mv && ci[u] < mi)) { mv = cv[u]; mi = ci[u]; }
        #pragma unroll
        for (int off = 32; off >= 1; off >>= 1) {
            float ov = __shfl_xor(mv, off);
            int   oi = __shfl_xor(mi, off);
            if (ov > mv || (ov == mv && oi < mi)) { mv = ov; mi = oi; }
        }
        sv[i] = mv; si[i] = mi;
        #pragma unroll
        for (int u = 0; u < 6; ++u)
            if (cv[u] == mv && ci[u] == mi) cv[u] = -INFINITY;
    }

    // exact fp32 re-rank of the 12 candidates
    const float* xt = x + rid * D;
    float4 xt4[4];
    #pragma unroll
    for (int c = 0; c < 4; ++c)
        xt4[c] = *(const float4*)(xt + (c << 8) + (lane << 2));
    float ex[NK];
    #pragma unroll
    for (int i = 0; i < NK; ++i) {
        bool val = si[i] >= 0;
        const float* xj = x + ((size_t)((b << 12) + (val ? si[i] : 0))) * D;
        float s = 0.f;
        #pragma unroll
        for (int c = 0; c < 4; ++c) {
            float4 v = *(const float4*)(xj + (c << 8) + (lane << 2));
            s += xt4[c].x * v.x + xt4[c].y * v.y + xt4[c].z * v.z + xt4[c].w * v.w;
        }
        #pragma unroll
        for (int off = 32; off >= 1; off >>= 1) s += __shfl_xor(s, off);
        ex[i] = val ? s : -INFINITY;
    }

    // exact top-8 (tie-break: lower index)
    float bv[8]; int bi[8];
    #pragma unroll
    for (int r = 0; r < 8; ++r) {
        int mp = 0;
        #pragma unroll
        for (int i = 1; i < NK; ++i) {
            bool better = (ex[i] > ex[mp]) ||
                          (ex[i] == ex[mp] && si[i] >= 0 &&
                           (si[mp] < 0 || si[i] < si[mp]));
            if (better) mp = i;
        }
        bv[r] = ex[mp]; bi[r] = si[mp];
        ex[mp] = -INFINITY;
    }

    // scores: lanes 8i..8i+7 compute dot(q[t], k[sel_i])
    int i8 = lane >> 3, e = lane & 7;
    bool v8 = bv[i8] > -1e37f;
    int g8 = v8 ? bi[i8] : 0;
    float4 qv = *(const float4*)(q + rid * DH + (e << 2));
    float4 kv = *(const float4*)(k + ((b << 12) + g8) * DH + (e << 2));
    float p = qv.x * kv.x + qv.y * kv.y + qv.z * kv.z + qv.w * kv.w;
    p += __shfl_xor(p, 1); p += __shfl_xor(p, 2); p += __shfl_xor(p, 4);
    p *= 0.17677669529663687f;               // 1/sqrt(32)

    float sc[8];
    #pragma unroll
    for (int i = 0; i < 8; ++i) sc[i] = __shfl(p, i << 3);

    float m = -INFINITY; int cnt = 0;
    #pragma unroll
    for (int i = 0; i < 8; ++i)
        if (bv[i] > -1e37f) { ++cnt; if (sc[i] > m) m = sc[i]; }

    float wgt[8]; float Z = 0.f; int gsel[8];
    #pragma unroll
    for (int i = 0; i < 8; ++i) {
        bool val = bv[i] > -1e37f;
        wgt[i] = val ? expf(sc[i] - m) : 0.f;
        Z += wgt[i];
        gsel[i] = val ? ((b << 12) + bi[i]) : (b << 12);
    }
    float invZ = (cnt > 0) ? 1.f / Z : 0.f;
    #pragma unroll
    for (int i = 0; i < 8; ++i) wgt[i] *= invZ;

    float* ot = out + rid * D;
    const float onemix = 1.f - mix;

    if (cnt == 0) {                          // t==0: uniform attention over ALL T
        const float* ms = meansum + (b << 10);
        for (int u = 0; u < 16; ++u) {
            int d = lane + (u << 6);
            float msg = ms[d] * (1.f / (float)T);
            float z = (mix * xt[d] + onemix * msg) * gain[d] + bias[d];
            ot[d] = 0.5f * z * (1.f + erff(z * 0.70710678118654752f)) * scale;
        }
    } else {
        const float* r0 = x + gsel[0] * D; const float* r1 = x + gsel[1] * D;
        const float* r2 = x + gsel[2] * D; const float* r3 = x + gsel[3] * D;
        const float* r4 = x + gsel[4] * D; const float* r5 = x + gsel[5] * D;
        const float* r6 = x + gsel[6] * D; const float* r7 = x + gsel[7] * D;
        for (int u = 0; u < 16; ++u) {
            int d = lane + (u << 6);
            float msg = wgt[0] * r0[d] + wgt[1] * r1[d] + wgt[2] * r2[d] + wgt[3] * r3[d]
                      + wgt[4] * r4[d] + wgt[5] * r5[d] + wgt[6] * r6[d] + wgt[7] * r7[d];
            float z = (mix * xt[d] + onemix * msg) * gain[d] + bias[d];
            ot[d] = 0.5f * z * (1.f + erff(z * 0.70710678118654752f)) * scale;
        }
    }
}

extern "C" void kernel_launch(void* const* d_in, const int* in_sizes, int n_in,
                              void* d_out, int out_size, void* d_ws, size_t ws_size,
                              hipStream_t stream)
{
    const float* x    = (const float*)d_in[0];
    const float* Wq   = (const float*)d_in[1];
    const float* Wk   = (const float*)d_in[2];
    const float* gain = (const float*)d_in[3];
    const float* bias = (const float*)d_in[4];
    const float* plm  = (const float*)d_in[5];
    const float* pls  = (const float*)d_in[6];
    float* out = (float*)d_out;

    float* ws      = (float*)d_ws;
    float* q       = ws;                       // 262144
    float* k       = ws + 262144;              // 262144
    float* meansum = ws + 524288;              // 2048
    float* pvals   = ws + 526336;              // B*T*CPR = 3145728
    int*   pidx    = (int*)(ws + 3672064);     // 3145728
    __bf16* xhi    = (__bf16*)(ws + 6817792);  // B*T*D bf16 = 8388608
    __bf16* xlo    = xhi + (size_t)B * T * D;
    __bf16* Whi    = xlo + (size_t)B * T * D;  // 64*1024 bf16 (Wq rows 0-31, Wk 32-63)
    __bf16* Wlo    = Whi + 64 * D;
    // total ws use: ~61.1 MB

    hipMemsetAsync(meansum, 0, 2048 * sizeof(float), stream);
    conv_kernel<<<B * T * D / 2048, 256, 0, stream>>>(x, xhi, xlo);
    conv_kernel<<<16, 256, 0, stream>>>(Wq, Whi, Wlo);
    conv_kernel<<<16, 256, 0, stream>>>(Wk, Whi + 32 * D, Wlo + 32 * D);
    mean_kernel<<<128, 256, 0, stream>>>(x, meansum);
    qk_mfma_kernel<<<B * T / 128, 256, 0, stream>>>(xhi, xlo, Whi, Wlo, q, k);
    topk_mfma_kernel<<<B * NBLK, 256, 0, stream>>>(xhi, xlo, pvals, pidx);
    attn_kernel<<<B * T / 4, 256, 0, stream>>>(x, q, k, meansum, pvals, pidx,
                                               gain, bias, plm, pls, out);
}

// Round 5
// 524.299 us; speedup vs baseline: 2.6324x; 1.0581x over previous
//
#include <hip/hip_runtime.h>
#include <math.h>

#define B 2
#define T 4096
#define D 1024
#define DH 32
#define TNB 32        // 128-row tiles per batch
#define NBLK 528      // TNB*(TNB+1)/2 causal tile pairs
#define NK 12         // per-chunk candidates kept (safety margin over 8)
#define CPR (32*NK)   // candidates per row = 384

typedef __bf16 bf16x8 __attribute__((ext_vector_type(8)));
typedef float f32x4 __attribute__((ext_vector_type(4)));

// ---------------- K_conv: src -> (hi, lo) bf16 split (2048 elems/block) -------
__global__ __launch_bounds__(256) void conv_kernel(const float* __restrict__ x,
        __bf16* __restrict__ xhi, __bf16* __restrict__ xlo)
{
    int i = (blockIdx.x * 256 + threadIdx.x) << 3;     // 8 floats/thread
    float4 a = *(const float4*)(x + i);
    float4 c = *(const float4*)(x + i + 4);
    float av[8] = {a.x, a.y, a.z, a.w, c.x, c.y, c.z, c.w};
    __bf16 h[8], l[8];
    #pragma unroll
    for (int j = 0; j < 8; ++j) {
        h[j] = (__bf16)av[j];
        l[j] = (__bf16)(av[j] - (float)h[j]);
    }
    *(float4*)(xhi + i) = *(float4*)h;
    *(float4*)(xlo + i) = *(float4*)l;
}

// ---------------- K0: per-batch column sums (for the t=0 row) ----------------
__global__ void mean_kernel(const float* __restrict__ x, float* __restrict__ meansum)
{
    int gid  = blockIdx.x;           // B * 4 dblk * 16 tch = 128 blocks
    int b    = gid >> 6;
    int rem  = gid & 63;
    int dblk = rem >> 4;
    int tch  = rem & 15;
    int d = dblk * 256 + threadIdx.x;
    const float* xp = x + (b * T + tch * 256) * D + d;
    float s = 0.f;
    #pragma unroll 8
    for (int it = 0; it < 256; ++it) s += xp[it * D];
    atomicAdd(&meansum[(b << 10) + d], s);
}

// ---------------- K1: q/k projection as split-bf16 MFMA GEMM -----------------
__global__ __launch_bounds__(256) void qk_mfma_kernel(
        const __bf16* __restrict__ xhi, const __bf16* __restrict__ xlo,
        const __bf16* __restrict__ Whi, const __bf16* __restrict__ Wlo,
        float* __restrict__ qo, float* __restrict__ ko)
{
    __shared__ __align__(16) __bf16 stg[15360];
    __bf16* sAhi = stg;            // 128 x 40
    __bf16* sAlo = stg + 5120;
    __bf16* sBhi = stg + 10240;    // 64 x 40
    __bf16* sBlo = stg + 12800;

    int tid = threadIdx.x;
    int m0 = blockIdx.x << 7;
    int w = tid >> 6, lane = tid & 63;
    int fr = lane & 15, fq = lane >> 4;

    int arow = tid >> 1, ah = tid & 1;      // A staging: 2 chunks of 16 bf16
    int brow = tid >> 2, bq = tid & 3;      // B staging: 4 chunks of 8 bf16

    const __bf16* gAh = xhi + (size_t)(m0 + arow) * D + ah * 16;
    const __bf16* gAl = xlo + (size_t)(m0 + arow) * D + ah * 16;
    const __bf16* gBh = Whi + brow * D + bq * 8;
    const __bf16* gBl = Wlo + brow * D + bq * 8;

    f32x4 acc[2][4];
    #pragma unroll
    for (int i = 0; i < 2; ++i)
        #pragma unroll
        for (int j = 0; j < 4; ++j) acc[i][j] = (f32x4){0.f, 0.f, 0.f, 0.f};

    float4 a0 = *(const float4*)(gAh);
    float4 a1 = *(const float4*)(gAh + 8);
    float4 a2 = *(const float4*)(gAl);
    float4 a3 = *(const float4*)(gAl + 8);
    float4 b0 = *(const float4*)(gBh);
    float4 b1 = *(const float4*)(gBl);

    int sa = arow * 40 + ah * 16;
    int sb = brow * 40 + bq * 8;

    for (int kc = 0; kc < 32; ++kc) {
        __syncthreads();
        *(float4*)(sAhi + sa) = a0;  *(float4*)(sAhi + sa + 8) = a1;
        *(float4*)(sAlo + sa) = a2;  *(float4*)(sAlo + sa + 8) = a3;
        *(float4*)(sBhi + sb) = b0;  *(float4*)(sBlo + sb) = b1;
        if (kc + 1 < 32) {
            int k0 = (kc + 1) << 5;
            a0 = *(const float4*)(gAh + k0);
            a1 = *(const float4*)(gAh + k0 + 8);
            a2 = *(const float4*)(gAl + k0);
            a3 = *(const float4*)(gAl + k0 + 8);
            b0 = *(const float4*)(gBh + k0);
            b1 = *(const float4*)(gBl + k0);
        }
        __syncthreads();
        bf16x8 fah[2], fal[2], fbh[4], fbl[4];
        #pragma unroll
        for (int i = 0; i < 2; ++i) {
            int r = (w << 5) + i * 16 + fr;
            fah[i] = *(const bf16x8*)(sAhi + r * 40 + fq * 8);
            fal[i] = *(const bf16x8*)(sAlo + r * 40 + fq * 8);
        }
        #pragma unroll
        for (int j = 0; j < 4; ++j) {
            int r = j * 16 + fr;
            fbh[j] = *(const bf16x8*)(sBhi + r * 40 + fq * 8);
            fbl[j] = *(const bf16x8*)(sBlo + r * 40 + fq * 8);
        }
        #pragma unroll
        for (int i = 0; i < 2; ++i)
            #pragma unroll
            for (int j = 0; j < 4; ++j) {
                acc[i][j] = __builtin_amdgcn_mfma_f32_16x16x32_bf16(fah[i], fbh[j], acc[i][j], 0, 0, 0);
                acc[i][j] = __builtin_amdgcn_mfma_f32_16x16x32_bf16(fah[i], fbl[j], acc[i][j], 0, 0, 0);
                acc[i][j] = __builtin_amdgcn_mfma_f32_16x16x32_bf16(fal[i], fbh[j], acc[i][j], 0, 0, 0);
            }
    }
    // writeout: C layout col=lane&15, row=fq*4+reg
    #pragma unroll
    for (int i = 0; i < 2; ++i) {
        int grow0 = m0 + (w << 5) + i * 16 + (fq << 2);
        #pragma unroll
        for (int j = 0; j < 4; ++j) {
            int gn = j * 16 + fr;
            float* dst = (gn < 32) ? (qo + grow0 * DH + gn)
                                   : (ko + grow0 * DH + gn - 32);
            dst[0]      = acc[i][j][0];
            dst[DH]     = acc[i][j][1];
            dst[2 * DH] = acc[i][j][2];
            dst[3 * DH] = acc[i][j][3];
        }
    }
}

// ---------------- K2: split-bf16 MFMA sim GEMM + per-row top-12 per 128-col chunk --
__global__ __launch_bounds__(256, 2) void topk_mfma_kernel(
        const __bf16* __restrict__ xhi, const __bf16* __restrict__ xlo,
        float* __restrict__ pvals, int* __restrict__ pidx)
{
    __shared__ __align__(16) float Sbuf[128 * 129];    // 66048 B
    __bf16* stg = (__bf16*)Sbuf;
    __bf16* sAhi = stg;
    __bf16* sAlo = stg + 5120;
    __bf16* sBhi = stg + 10240;
    __bf16* sBlo = stg + 15360;

    int tid = threadIdx.x;
    int b = blockIdx.x / NBLK;
    int l = blockIdx.x - b * NBLK;
    int rt = (int)((sqrtf(8.f * l + 1.f) - 1.f) * 0.5f);
    while ((rt + 1) * (rt + 2) / 2 <= l) ++rt;
    while (rt * (rt + 1) / 2 > l) --rt;
    int ct = l - rt * (rt + 1) / 2;
    int r0 = rt << 7, c0 = ct << 7;
    int base = b * T;

    int w = tid >> 6, lane = tid & 63;
    int wr = (w >> 1) << 6, wc = (w & 1) << 6;
    bool active = !(rt == ct && w == 1);   // diag block, fully non-causal quadrant

    int srow = tid >> 2, sq = tid & 3;     // staging: thread -> (row, 16B chunk)
    int fr = lane & 15, fq = lane >> 4;    // fragment: row-in-tile, k-quad

    const __bf16* gAh = xhi + (base + r0) * D;
    const __bf16* gAl = xlo + (base + r0) * D;
    const __bf16* gBh = xhi + (base + c0) * D;
    const __bf16* gBl = xlo + (base + c0) * D;

    f32x4 acc[4][4];
    #pragma unroll
    for (int i = 0; i < 4; ++i)
        #pragma unroll
        for (int j = 0; j < 4; ++j) acc[i][j] = (f32x4){0.f, 0.f, 0.f, 0.f};

    int o0 = srow * D + sq * 8;
    int o1 = o0 + 64 * D;
    float4 pf0 = *(const float4*)(gAh + o0);
    float4 pf1 = *(const float4*)(gAh + o1);
    float4 pf2 = *(const float4*)(gAl + o0);
    float4 pf3 = *(const float4*)(gAl + o1);
    float4 pf4 = *(const float4*)(gBh + o0);
    float4 pf5 = *(const float4*)(gBh + o1);
    float4 pf6 = *(const float4*)(gBl + o0);
    float4 pf7 = *(const float4*)(gBl + o1);

    int s0 = srow * 40 + sq * 8;
    int s1 = s0 + 64 * 40;

    for (int kc = 0; kc < 32; ++kc) {
        __syncthreads();
        *(float4*)(sAhi + s0) = pf0;  *(float4*)(sAhi + s1) = pf1;
        *(float4*)(sAlo + s0) = pf2;  *(float4*)(sAlo + s1) = pf3;
        *(float4*)(sBhi + s0) = pf4;  *(float4*)(sBhi + s1) = pf5;
        *(float4*)(sBlo + s0) = pf6;  *(float4*)(sBlo + s1) = pf7;
        if (kc + 1 < 32) {
            int k0 = (kc + 1) << 5;
            int n0 = srow * D + k0 + sq * 8;
            int n1 = n0 + 64 * D;
            pf0 = *(const float4*)(gAh + n0);
            pf1 = *(const float4*)(gAh + n1);
            pf2 = *(const float4*)(gAl + n0);
            pf3 = *(const float4*)(gAl + n1);
            pf4 = *(const float4*)(gBh + n0);
            pf5 = *(const float4*)(gBh + n1);
            pf6 = *(const float4*)(gBl + n0);
            pf7 = *(const float4*)(gBl + n1);
        }
        __syncthreads();
        if (active) {
            bf16x8 ah[4], al[4], bh[4], bl[4];
            #pragma unroll
            for (int i = 0; i < 4; ++i) {
                int ar = wr + i * 16 + fr;
                ah[i] = *(const bf16x8*)(sAhi + ar * 40 + fq * 8);
                al[i] = *(const bf16x8*)(sAlo + ar * 40 + fq * 8);
                int bc = wc + i * 16 + fr;
                bh[i] = *(const bf16x8*)(sBhi + bc * 40 + fq * 8);
                bl[i] = *(const bf16x8*)(sBlo + bc * 40 + fq * 8);
            }
            #pragma unroll
            for (int i = 0; i < 4; ++i)
                #pragma unroll
                for (int j = 0; j < 4; ++j) {
                    acc[i][j] = __builtin_amdgcn_mfma_f32_16x16x32_bf16(ah[i], bh[j], acc[i][j], 0, 0, 0);
                    acc[i][j] = __builtin_amdgcn_mfma_f32_16x16x32_bf16(ah[i], bl[j], acc[i][j], 0, 0, 0);
                    acc[i][j] = __builtin_amdgcn_mfma_f32_16x16x32_bf16(al[i], bh[j], acc[i][j], 0, 0, 0);
                }
        }
    }
    __syncthreads();
    {   // write S: C layout col=lane&15, row=(lane>>4)*4+reg
        int cr = fq << 2, cc = fr;
        #pragma unroll
        for (int i = 0; i < 4; ++i)
            #pragma unroll
            for (int j = 0; j < 4; ++j) {
                float* sp = Sbuf + (wr + i * 16 + cr) * 129 + wc + j * 16 + cc;
                sp[0]       = acc[i][j][0];
                sp[129]     = acc[i][j][1];
                sp[2 * 129] = acc[i][j][2];
                sp[3 * 129] = acc[i][j][3];
            }
    }
    __syncthreads();
    if (tid < 128) {                       // per-row top-12 over this 128-col chunk
        int gt = r0 + tid;
        int cmax = gt - c0;
        if (cmax > 128) cmax = 128;
        if (cmax < 0) cmax = 0;
        float tv[NK]; int ti[NK];
        #pragma unroll
        for (int i = 0; i < NK; ++i) { tv[i] = -INFINITY; ti[i] = -1; }
        float vmin = -INFINITY; int minp = 0;
        const float* Srow = Sbuf + tid * 129;
        for (int c = 0; c < cmax; ++c) {
            float v = Srow[c];
            if (v > vmin) {
                tv[minp] = v; ti[minp] = c0 + c;
                vmin = tv[0]; minp = 0;
                #pragma unroll
                for (int i = 1; i < NK; ++i)
                    if (tv[i] < vmin) { vmin = tv[i]; minp = i; }
            }
        }
        int ob = (base + gt) * CPR + ct * NK;
        #pragma unroll
        for (int i = 0; i < NK; ++i) { pvals[ob + i] = tv[i]; pidx[ob + i] = ti[i]; }
    }
}

// ---------------- K3: block-per-row select + attention + gelu -----------------
// Phases: A stage cands->LDS | B wave0 butterfly top-12 | C 4-wave exact re-rank
//         D wave0 top-8 + scores + softmax | E block-wide float4 epilogue
__global__ __launch_bounds__(256) void attn2_kernel(const float* __restrict__ x,
        const float* __restrict__ q, const float* __restrict__ k,
        const float* __restrict__ meansum,
        const float* __restrict__ pvals, const int* __restrict__ pidx,
        const float* __restrict__ gain, const float* __restrict__ bias,
        const float* __restrict__ plm, const float* __restrict__ pls,
        float* __restrict__ out)
{
    __shared__ float Lsv[CPR];
    __shared__ int   Lsi[CPR];
    __shared__ float Mtv[NK];
    __shared__ int   Mti[NK];
    __shared__ float Lex[NK];
    __shared__ float Lw[8];
    __shared__ int   Lg[8];
    __shared__ int   Lcnt;

    int tid = threadIdx.x;
    int w = tid >> 6, lane = tid & 63;
    int rid = blockIdx.x;                    // global row b*T+t
    int b = rid >> 12, t = rid & (T - 1);
    int ncand = NK * ((t + 127) >> 7);

    // ---- Phase A: stage candidates (poison-masked beyond ncand) ----
    if (tid < CPR / 4) {
        float4 v = *(const float4*)(pvals + (size_t)rid * CPR + (tid << 2));
        int4  ii = *(const int4*)(pidx + (size_t)rid * CPR + (tid << 2));
        int c = tid << 2;
        Lsv[c]     = (c     < ncand) ? v.x : -INFINITY;
        Lsv[c + 1] = (c + 1 < ncand) ? v.y : -INFINITY;
        Lsv[c + 2] = (c + 2 < ncand) ? v.z : -INFINITY;
        Lsv[c + 3] = (c + 3 < ncand) ? v.w : -INFINITY;
        Lsi[c]     = (c     < ncand) ? ii.x : -1;
        Lsi[c + 1] = (c + 1 < ncand) ? ii.y : -1;
        Lsi[c + 2] = (c + 2 < ncand) ? ii.z : -1;
        Lsi[c + 3] = (c + 3 < ncand) ? ii.w : -1;
    }
    __syncthreads();

    // ---- Phase B: wave 0 butterfly -> approx top-12 ----
    if (w == 0) {
        float cv[6]; int ci[6];
        #pragma unroll
        for (int u = 0; u < 6; ++u) {
            cv[u] = Lsv[lane + (u << 6)];
            ci[u] = Lsi[lane + (u << 6)];
        }
        #pragma unroll
        for (int i = 0; i < NK; ++i) {
            float mv = cv[0]; int mi = ci[0];
            #pragma unroll
            for (int u = 1; u < 6; ++u)
                if (cv[u] > mv || (cv[u] == mv && ci[u] < mi)) { mv = cv[u]; mi = ci[u]; }
            #pragma unroll
            for (int off = 32; off >= 1; off >>= 1) {
                float ov = __shfl_xor(mv, off);
                int   oi = __shfl_xor(mi, off);
                if (ov > mv || (ov == mv && oi < mi)) { mv = ov; mi = oi; }
            }
            if (lane == 0) { Mtv[i] = mv; Mti[i] = mi; }
            #pragma unroll
            for (int u = 0; u < 6; ++u)
                if (cv[u] == mv && ci[u] == mi) cv[u] = -INFINITY;
        }
    }
    __syncthreads();

    // ---- Phase C: exact fp32 re-rank, 3 candidates per wave ----
    const float* xt = x + (size_t)rid * D;
    {
        float4 xt4[4];
        #pragma unroll
        for (int c = 0; c < 4; ++c)
            xt4[c] = *(const float4*)(xt + (c << 8) + (lane << 2));
        #pragma unroll
        for (int s = 0; s < 3; ++s) {
            int i = w + (s << 2);
            int sj = Mti[i];
            bool val = sj >= 0;
            const float* xj = x + (size_t)((b << 12) + (val ? sj : 0)) * D;
            float ss = 0.f;
            #pragma unroll
            for (int c = 0; c < 4; ++c) {
                float4 v = *(const float4*)(xj + (c << 8) + (lane << 2));
                ss += xt4[c].x * v.x + xt4[c].y * v.y + xt4[c].z * v.z + xt4[c].w * v.w;
            }
            #pragma unroll
            for (int off = 32; off >= 1; off >>= 1) ss += __shfl_xor(ss, off);
            if (lane == 0) Lex[i] = val ? ss : -INFINITY;
        }
    }
    __syncthreads();

    // ---- Phase D: wave 0: exact top-8, scores, softmax ----
    if (w == 0) {
        float ex[NK]; int si[NK];
        #pragma unroll
        for (int i = 0; i < NK; ++i) { ex[i] = Lex[i]; si[i] = Mti[i]; }
        float bv[8]; int bi[8];
        #pragma unroll
        for (int r = 0; r < 8; ++r) {
            int mp = 0;
            #pragma unroll
            for (int i = 1; i < NK; ++i) {
                bool better = (ex[i] > ex[mp]) ||
                              (ex[i] == ex[mp] && si[i] >= 0 &&
                               (si[mp] < 0 || si[i] < si[mp]));
                if (better) mp = i;
            }
            bv[r] = ex[mp]; bi[r] = si[mp];
            ex[mp] = -INFINITY;
        }
        int i8 = lane >> 3, e = lane & 7;
        bool v8 = bv[i8] > -1e37f;
        int g8 = v8 ? bi[i8] : 0;
        float4 qv = *(const float4*)(q + (size_t)rid * DH + (e << 2));
        float4 kv = *(const float4*)(k + (size_t)((b << 12) + g8) * DH + (e << 2));
        float p = qv.x * kv.x + qv.y * kv.y + qv.z * kv.z + qv.w * kv.w;
        p += __shfl_xor(p, 1); p += __shfl_xor(p, 2); p += __shfl_xor(p, 4);
        p *= 0.17677669529663687f;           // 1/sqrt(32)
        float sc[8];
        #pragma unroll
        for (int i = 0; i < 8; ++i) sc[i] = __shfl(p, i << 3);
        float m = -INFINITY; int cnt = 0;
        #pragma unroll
        for (int i = 0; i < 8; ++i)
            if (bv[i] > -1e37f) { ++cnt; if (sc[i] > m) m = sc[i]; }
        float wgt[8]; float Z = 0.f;
        #pragma unroll
        for (int i = 0; i < 8; ++i) {
            bool val = bv[i] > -1e37f;
            wgt[i] = val ? expf(sc[i] - m) : 0.f;
            Z += wgt[i];
        }
        float invZ = (cnt > 0) ? 1.f / Z : 0.f;
        if (lane < 8) {
            Lw[lane] = wgt[lane] * invZ;
            Lg[lane] = (bv[lane] > -1e37f) ? ((b << 12) + bi[lane]) : (b << 12);
        }
        if (lane == 0) Lcnt = cnt;
    }
    __syncthreads();

    // ---- Phase E: epilogue, 4 dims per thread (float4) ----
    float mix   = 1.f / (1.f + expf(-plm[0]));
    float scale = log1pf(expf(pls[0])) + 0.01f;
    const float onemix = 1.f - mix;
    int d0 = tid << 2;
    float4 xv = *(const float4*)(xt + d0);
    float4 g4 = *(const float4*)(gain + d0);
    float4 b4 = *(const float4*)(bias + d0);
    float4 msg;
    if (Lcnt == 0) {                         // t==0: uniform attention over ALL T
        float4 ms = *(const float4*)(meansum + (b << 10) + d0);
        msg.x = ms.x * (1.f / (float)T); msg.y = ms.y * (1.f / (float)T);
        msg.z = ms.z * (1.f / (float)T); msg.w = ms.w * (1.f / (float)T);
    } else {
        msg = (float4){0.f, 0.f, 0.f, 0.f};
        #pragma unroll
        for (int i = 0; i < 8; ++i) {
            float wi = Lw[i];
            const float4 rv = *(const float4*)(x + (size_t)Lg[i] * D + d0);
            msg.x += wi * rv.x; msg.y += wi * rv.y;
            msg.z += wi * rv.z; msg.w += wi * rv.w;
        }
    }
    float zi[4] = {
        (mix * xv.x + onemix * msg.x) * g4.x + b4.x,
        (mix * xv.y + onemix * msg.y) * g4.y + b4.y,
        (mix * xv.z + onemix * msg.z) * g4.z + b4.z,
        (mix * xv.w + onemix * msg.w) * g4.w + b4.w };
    float4 o4;
    o4.x = 0.5f * zi[0] * (1.f + erff(zi[0] * 0.70710678118654752f)) * scale;
    o4.y = 0.5f * zi[1] * (1.f + erff(zi[1] * 0.70710678118654752f)) * scale;
    o4.z = 0.5f * zi[2] * (1.f + erff(zi[2] * 0.70710678118654752f)) * scale;
    o4.w = 0.5f * zi[3] * (1.f + erff(zi[3] * 0.70710678118654752f)) * scale;
    *(float4*)(out + (size_t)rid * D + d0) = o4;
}

extern "C" void kernel_launch(void* const* d_in, const int* in_sizes, int n_in,
                              void* d_out, int out_size, void* d_ws, size_t ws_size,
                              hipStream_t stream)
{
    const float* x    = (const float*)d_in[0];
    const float* Wq   = (const float*)d_in[1];
    const float* Wk   = (const float*)d_in[2];
    const float* gain = (const float*)d_in[3];
    const float* bias = (const float*)d_in[4];
    const float* plm  = (const float*)d_in[5];
    const float* pls  = (const float*)d_in[6];
    float* out = (float*)d_out;

    float* ws      = (float*)d_ws;
    float* q       = ws;                       // 262144
    float* k       = ws + 262144;              // 262144
    float* meansum = ws + 524288;              // 2048
    float* pvals   = ws + 526336;              // B*T*CPR = 3145728
    int*   pidx    = (int*)(ws + 3672064);     // 3145728
    __bf16* xhi    = (__bf16*)(ws + 6817792);  // B*T*D bf16 = 8388608
    __bf16* xlo    = xhi + (size_t)B * T * D;
    __bf16* Whi    = xlo + (size_t)B * T * D;  // 64*1024 bf16 (Wq rows 0-31, Wk 32-63)
    __bf16* Wlo    = Whi + 64 * D;
    // total ws use: ~61.1 MB

    hipMemsetAsync(meansum, 0, 2048 * sizeof(float), stream);
    conv_kernel<<<B * T * D / 2048, 256, 0, stream>>>(x, xhi, xlo);
    conv_kernel<<<16, 256, 0, stream>>>(Wq, Whi, Wlo);
    conv_kernel<<<16, 256, 0, stream>>>(Wk, Whi + 32 * D, Wlo + 32 * D);
    mean_kernel<<<128, 256, 0, stream>>>(x, meansum);
    qk_mfma_kernel<<<B * T / 128, 256, 0, stream>>>(xhi, xlo, Whi, Wlo, q, k);
    topk_mfma_kernel<<<B * NBLK, 256, 0, stream>>>(xhi, xlo, pvals, pidx);
    attn2_kernel<<<B * T, 256, 0, stream>>>(x, q, k, meansum, pvals, pidx,
                                            gain, bias, plm, pls, out);
}

// Round 6
// 465.783 us; speedup vs baseline: 2.9631x; 1.1256x over previous
//
#include <hip/hip_runtime.h>
#include <math.h>

#define B 2
#define T 4096
#define D 1024
#define DH 32
#define TNB 32        // 128-row tiles per batch
#define NBLK 528      // TNB*(TNB+1)/2 causal tile pairs
#define NK 12         // per-chunk candidates kept (safety margin over 8)
#define CPR (32*NK)   // candidates per row = 384

typedef __bf16 bf16x8 __attribute__((ext_vector_type(8)));
typedef float f32x4 __attribute__((ext_vector_type(4)));

// ---------------- K_conv: src -> (hi, lo) bf16 split (2048 elems/block) -------
__global__ __launch_bounds__(256) void conv_kernel(const float* __restrict__ x,
        __bf16* __restrict__ xhi, __bf16* __restrict__ xlo)
{
    int i = (blockIdx.x * 256 + threadIdx.x) << 3;     // 8 floats/thread
    float4 a = *(const float4*)(x + i);
    float4 c = *(const float4*)(x + i + 4);
    float av[8] = {a.x, a.y, a.z, a.w, c.x, c.y, c.z, c.w};
    __bf16 h[8], l[8];
    #pragma unroll
    for (int j = 0; j < 8; ++j) {
        h[j] = (__bf16)av[j];
        l[j] = (__bf16)(av[j] - (float)h[j]);
    }
    *(float4*)(xhi + i) = *(float4*)h;
    *(float4*)(xlo + i) = *(float4*)l;
}

// ---------------- K0: per-batch column sums (for the t=0 row) ----------------
__global__ void mean_kernel(const float* __restrict__ x, float* __restrict__ meansum)
{
    int gid  = blockIdx.x;           // B * 4 dblk * 16 tch = 128 blocks
    int b    = gid >> 6;
    int rem  = gid & 63;
    int dblk = rem >> 4;
    int tch  = rem & 15;
    int d = dblk * 256 + threadIdx.x;
    const float* xp = x + (b * T + tch * 256) * D + d;
    float s = 0.f;
    #pragma unroll 8
    for (int it = 0; it < 256; ++it) s += xp[it * D];
    atomicAdd(&meansum[(b << 10) + d], s);
}

// ---------------- K1: q/k projection as split-bf16 MFMA GEMM -----------------
__global__ __launch_bounds__(256) void qk_mfma_kernel(
        const __bf16* __restrict__ xhi, const __bf16* __restrict__ xlo,
        const __bf16* __restrict__ Whi, const __bf16* __restrict__ Wlo,
        float* __restrict__ qo, float* __restrict__ ko)
{
    __shared__ __align__(16) __bf16 stg[15360];
    __bf16* sAhi = stg;            // 128 x 40
    __bf16* sAlo = stg + 5120;
    __bf16* sBhi = stg + 10240;    // 64 x 40
    __bf16* sBlo = stg + 12800;

    int tid = threadIdx.x;
    int m0 = blockIdx.x << 7;
    int w = tid >> 6, lane = tid & 63;
    int fr = lane & 15, fq = lane >> 4;

    int arow = tid >> 1, ah = tid & 1;      // A staging: 2 chunks of 16 bf16
    int brow = tid >> 2, bq = tid & 3;      // B staging: 4 chunks of 8 bf16

    const __bf16* gAh = xhi + (size_t)(m0 + arow) * D + ah * 16;
    const __bf16* gAl = xlo + (size_t)(m0 + arow) * D + ah * 16;
    const __bf16* gBh = Whi + brow * D + bq * 8;
    const __bf16* gBl = Wlo + brow * D + bq * 8;

    f32x4 acc[2][4];
    #pragma unroll
    for (int i = 0; i < 2; ++i)
        #pragma unroll
        for (int j = 0; j < 4; ++j) acc[i][j] = (f32x4){0.f, 0.f, 0.f, 0.f};

    float4 a0 = *(const float4*)(gAh);
    float4 a1 = *(const float4*)(gAh + 8);
    float4 a2 = *(const float4*)(gAl);
    float4 a3 = *(const float4*)(gAl + 8);
    float4 b0 = *(const float4*)(gBh);
    float4 b1 = *(const float4*)(gBl);

    int sa = arow * 40 + ah * 16;
    int sb = brow * 40 + bq * 8;

    for (int kc = 0; kc < 32; ++kc) {
        __syncthreads();
        *(float4*)(sAhi + sa) = a0;  *(float4*)(sAhi + sa + 8) = a1;
        *(float4*)(sAlo + sa) = a2;  *(float4*)(sAlo + sa + 8) = a3;
        *(float4*)(sBhi + sb) = b0;  *(float4*)(sBlo + sb) = b1;
        if (kc + 1 < 32) {
            int k0 = (kc + 1) << 5;
            a0 = *(const float4*)(gAh + k0);
            a1 = *(const float4*)(gAh + k0 + 8);
            a2 = *(const float4*)(gAl + k0);
            a3 = *(const float4*)(gAl + k0 + 8);
            b0 = *(const float4*)(gBh + k0);
            b1 = *(const float4*)(gBl + k0);
        }
        __syncthreads();
        bf16x8 fah[2], fal[2], fbh[4], fbl[4];
        #pragma unroll
        for (int i = 0; i < 2; ++i) {
            int r = (w << 5) + i * 16 + fr;
            fah[i] = *(const bf16x8*)(sAhi + r * 40 + fq * 8);
            fal[i] = *(const bf16x8*)(sAlo + r * 40 + fq * 8);
        }
        #pragma unroll
        for (int j = 0; j < 4; ++j) {
            int r = j * 16 + fr;
            fbh[j] = *(const bf16x8*)(sBhi + r * 40 + fq * 8);
            fbl[j] = *(const bf16x8*)(sBlo + r * 40 + fq * 8);
        }
        #pragma unroll
        for (int i = 0; i < 2; ++i)
            #pragma unroll
            for (int j = 0; j < 4; ++j) {
                acc[i][j] = __builtin_amdgcn_mfma_f32_16x16x32_bf16(fah[i], fbh[j], acc[i][j], 0, 0, 0);
                acc[i][j] = __builtin_amdgcn_mfma_f32_16x16x32_bf16(fah[i], fbl[j], acc[i][j], 0, 0, 0);
                acc[i][j] = __builtin_amdgcn_mfma_f32_16x16x32_bf16(fal[i], fbh[j], acc[i][j], 0, 0, 0);
            }
    }
    // writeout: C layout col=lane&15, row=fq*4+reg
    #pragma unroll
    for (int i = 0; i < 2; ++i) {
        int grow0 = m0 + (w << 5) + i * 16 + (fq << 2);
        #pragma unroll
        for (int j = 0; j < 4; ++j) {
            int gn = j * 16 + fr;
            float* dst = (gn < 32) ? (qo + grow0 * DH + gn)
                                   : (ko + grow0 * DH + gn - 32);
            dst[0]      = acc[i][j][0];
            dst[DH]     = acc[i][j][1];
            dst[2 * DH] = acc[i][j][2];
            dst[3 * DH] = acc[i][j][3];
        }
    }
}

// ---------------- K2: split-bf16 MFMA sim GEMM + per-row top-12 per 128-col chunk --
__global__ __launch_bounds__(256, 2) void topk_mfma_kernel(
        const __bf16* __restrict__ xhi, const __bf16* __restrict__ xlo,
        float* __restrict__ pvals, int* __restrict__ pidx)
{
    __shared__ __align__(16) float Sbuf[128 * 129];    // 66048 B
    __bf16* stg = (__bf16*)Sbuf;
    __bf16* sAhi = stg;
    __bf16* sAlo = stg + 5120;
    __bf16* sBhi = stg + 10240;
    __bf16* sBlo = stg + 15360;

    int tid = threadIdx.x;
    int b = blockIdx.x / NBLK;
    int l = blockIdx.x - b * NBLK;
    int rt = (int)((sqrtf(8.f * l + 1.f) - 1.f) * 0.5f);
    while ((rt + 1) * (rt + 2) / 2 <= l) ++rt;
    while (rt * (rt + 1) / 2 > l) --rt;
    int ct = l - rt * (rt + 1) / 2;
    int r0 = rt << 7, c0 = ct << 7;
    int base = b * T;

    int w = tid >> 6, lane = tid & 63;
    int wr = (w >> 1) << 6, wc = (w & 1) << 6;
    bool active = !(rt == ct && w == 1);   // diag block, fully non-causal quadrant

    int srow = tid >> 2, sq = tid & 3;     // staging: thread -> (row, 16B chunk)
    int fr = lane & 15, fq = lane >> 4;    // fragment: row-in-tile, k-quad

    const __bf16* gAh = xhi + (base + r0) * D;
    const __bf16* gAl = xlo + (base + r0) * D;
    const __bf16* gBh = xhi + (base + c0) * D;
    const __bf16* gBl = xlo + (base + c0) * D;

    f32x4 acc[4][4];
    #pragma unroll
    for (int i = 0; i < 4; ++i)
        #pragma unroll
        for (int j = 0; j < 4; ++j) acc[i][j] = (f32x4){0.f, 0.f, 0.f, 0.f};

    int o0 = srow * D + sq * 8;
    int o1 = o0 + 64 * D;
    float4 pf0 = *(const float4*)(gAh + o0);
    float4 pf1 = *(const float4*)(gAh + o1);
    float4 pf2 = *(const float4*)(gAl + o0);
    float4 pf3 = *(const float4*)(gAl + o1);
    float4 pf4 = *(const float4*)(gBh + o0);
    float4 pf5 = *(const float4*)(gBh + o1);
    float4 pf6 = *(const float4*)(gBl + o0);
    float4 pf7 = *(const float4*)(gBl + o1);

    int s0 = srow * 40 + sq * 8;
    int s1 = s0 + 64 * 40;

    for (int kc = 0; kc < 32; ++kc) {
        __syncthreads();
        *(float4*)(sAhi + s0) = pf0;  *(float4*)(sAhi + s1) = pf1;
        *(float4*)(sAlo + s0) = pf2;  *(float4*)(sAlo + s1) = pf3;
        *(float4*)(sBhi + s0) = pf4;  *(float4*)(sBhi + s1) = pf5;
        *(float4*)(sBlo + s0) = pf6;  *(float4*)(sBlo + s1) = pf7;
        if (kc + 1 < 32) {
            int k0 = (kc + 1) << 5;
            int n0 = srow * D + k0 + sq * 8;
            int n1 = n0 + 64 * D;
            pf0 = *(const float4*)(gAh + n0);
            pf1 = *(const float4*)(gAh + n1);
            pf2 = *(const float4*)(gAl + n0);
            pf3 = *(const float4*)(gAl + n1);
            pf4 = *(const float4*)(gBh + n0);
            pf5 = *(const float4*)(gBh + n1);
            pf6 = *(const float4*)(gBl + n0);
            pf7 = *(const float4*)(gBl + n1);
        }
        __syncthreads();
        if (active) {
            bf16x8 ah[4], al[4], bh[4], bl[4];
            #pragma unroll
            for (int i = 0; i < 4; ++i) {
                int ar = wr + i * 16 + fr;
                ah[i] = *(const bf16x8*)(sAhi + ar * 40 + fq * 8);
                al[i] = *(const bf16x8*)(sAlo + ar * 40 + fq * 8);
                int bc = wc + i * 16 + fr;
                bh[i] = *(const bf16x8*)(sBhi + bc * 40 + fq * 8);
                bl[i] = *(const bf16x8*)(sBlo + bc * 40 + fq * 8);
            }
            #pragma unroll
            for (int i = 0; i < 4; ++i)
                #pragma unroll
                for (int j = 0; j < 4; ++j) {
                    acc[i][j] = __builtin_amdgcn_mfma_f32_16x16x32_bf16(ah[i], bh[j], acc[i][j], 0, 0, 0);
                    acc[i][j] = __builtin_amdgcn_mfma_f32_16x16x32_bf16(ah[i], bl[j], acc[i][j], 0, 0, 0);
                    acc[i][j] = __builtin_amdgcn_mfma_f32_16x16x32_bf16(al[i], bh[j], acc[i][j], 0, 0, 0);
                }
        }
    }
    __syncthreads();
    {   // write S: C layout col=lane&15, row=(lane>>4)*4+reg
        int cr = fq << 2, cc = fr;
        #pragma unroll
        for (int i = 0; i < 4; ++i)
            #pragma unroll
            for (int j = 0; j < 4; ++j) {
                float* sp = Sbuf + (wr + i * 16 + cr) * 129 + wc + j * 16 + cc;
                sp[0]       = acc[i][j][0];
                sp[129]     = acc[i][j][1];
                sp[2 * 129] = acc[i][j][2];
                sp[3 * 129] = acc[i][j][3];
            }
    }
    __syncthreads();
    if (tid < 128) {                       // per-row top-12 over this 128-col chunk
        int gt = r0 + tid;
        int cmax = gt - c0;
        if (cmax > 128) cmax = 128;
        if (cmax < 0) cmax = 0;
        float tv[NK]; int ti[NK];
        #pragma unroll
        for (int i = 0; i < NK; ++i) { tv[i] = -INFINITY; ti[i] = -1; }
        float vmin = -INFINITY; int minp = 0;
        const float* Srow = Sbuf + tid * 129;
        for (int c = 0; c < cmax; ++c) {
            float v = Srow[c];
            if (v > vmin) {
                tv[minp] = v; ti[minp] = c0 + c;
                vmin = tv[0]; minp = 0;
                #pragma unroll
                for (int i = 1; i < NK; ++i)
                    if (tv[i] < vmin) { vmin = tv[i]; minp = i; }
            }
        }
        int ob = (base + gt) * CPR + ct * NK;
        #pragma unroll
        for (int i = 0; i < NK; ++i) { pvals[ob + i] = tv[i]; pidx[ob + i] = ti[i]; }
    }
}

// ---------------- K3a: wave-per-row selection (barrier-free) ------------------
// merge 384 cands -> approx top-12 -> exact fp32 re-rank (batched loads)
// -> top-8 -> q.k scores -> softmax -> write 8 (weight, global row) pairs.
__global__ __launch_bounds__(256) void select_kernel(const float* __restrict__ x,
        const float* __restrict__ q, const float* __restrict__ k,
        const float* __restrict__ pvals, const int* __restrict__ pidx,
        float* __restrict__ selw, int* __restrict__ selg)
{
    int tid = threadIdx.x;
    int w = tid >> 6, lane = tid & 63;
    int rid = (blockIdx.x << 2) + w;         // global row b*T+t
    int b = rid >> 12, t = rid & (T - 1);
    int ncand = NK * ((t + 127) >> 7);

    // candidate loads (all in flight)
    float cv[6]; int ci[6];
    #pragma unroll
    for (int u = 0; u < 6; ++u) {
        int cid = lane + (u << 6);
        bool val = cid < ncand;
        cv[u] = val ? pvals[(size_t)rid * CPR + cid] : -INFINITY;
        ci[u] = val ? pidx[(size_t)rid * CPR + cid] : -1;
    }
    // prefetch xt fragments (independent of merge)
    const float* xt = x + (size_t)rid * D;
    float4 xt4[4];
    #pragma unroll
    for (int c = 0; c < 4; ++c)
        xt4[c] = *(const float4*)(xt + (c << 8) + (lane << 2));

    // butterfly merge -> approx top-12 (identical logic/tie-breaks)
    float sv[NK]; int si[NK];
    #pragma unroll
    for (int i = 0; i < NK; ++i) {
        float mv = cv[0]; int mi = ci[0];
        #pragma unroll
        for (int u = 1; u < 6; ++u)
            if (cv[u] > mv || (cv[u] == mv && ci[u] < mi)) { mv = cv[u]; mi = ci[u]; }
        #pragma unroll
        for (int off = 32; off >= 1; off >>= 1) {
            float ov = __shfl_xor(mv, off);
            int   oi = __shfl_xor(mi, off);
            if (ov > mv || (ov == mv && oi < mi)) { mv = ov; mi = oi; }
        }
        sv[i] = mv; si[i] = mi;
        #pragma unroll
        for (int u = 0; u < 6; ++u)
            if (cv[u] == mv && ci[u] == mi) cv[u] = -INFINITY;
    }

    // exact fp32 re-rank: 4 batches of 3 candidates, loads batched in flight
    float ex[NK];
    #pragma unroll
    for (int batch = 0; batch < 4; ++batch) {
        float4 rv[3][4];
        #pragma unroll
        for (int s = 0; s < 3; ++s) {
            int i = batch * 3 + s;
            int sj = si[i];
            const float* xj = x + (size_t)((b << 12) + (sj >= 0 ? sj : 0)) * D;
            #pragma unroll
            for (int c = 0; c < 4; ++c)
                rv[s][c] = *(const float4*)(xj + (c << 8) + (lane << 2));
        }
        #pragma unroll
        for (int s = 0; s < 3; ++s) {
            float ss = 0.f;
            #pragma unroll
            for (int c = 0; c < 4; ++c)
                ss += xt4[c].x * rv[s][c].x + xt4[c].y * rv[s][c].y
                    + xt4[c].z * rv[s][c].z + xt4[c].w * rv[s][c].w;
            ex[batch * 3 + s] = ss;
        }
    }
    // shuffle-reduce all 12 (independent chains pipeline)
    #pragma unroll
    for (int i = 0; i < NK; ++i) {
        float ssum = ex[i];
        #pragma unroll
        for (int off = 32; off >= 1; off >>= 1) ssum += __shfl_xor(ssum, off);
        ex[i] = (si[i] >= 0) ? ssum : -INFINITY;
    }

    // exact top-8 (tie-break: lower index) — every lane computes identically
    float bv[8]; int bi[8];
    #pragma unroll
    for (int r = 0; r < 8; ++r) {
        int mp = 0;
        #pragma unroll
        for (int i = 1; i < NK; ++i) {
            bool better = (ex[i] > ex[mp]) ||
                          (ex[i] == ex[mp] && si[i] >= 0 &&
                           (si[mp] < 0 || si[i] < si[mp]));
            if (better) mp = i;
        }
        bv[r] = ex[mp]; bi[r] = si[mp];
        ex[mp] = -INFINITY;
    }

    // scores: lanes 8i..8i+7 compute dot(q[t], k[sel_i])
    int i8 = lane >> 3, e = lane & 7;
    bool v8 = bv[i8] > -1e37f;
    int g8 = v8 ? bi[i8] : 0;
    float4 qv = *(const float4*)(q + (size_t)rid * DH + (e << 2));
    float4 kv = *(const float4*)(k + (size_t)((b << 12) + g8) * DH + (e << 2));
    float p = qv.x * kv.x + qv.y * kv.y + qv.z * kv.z + qv.w * kv.w;
    p += __shfl_xor(p, 1); p += __shfl_xor(p, 2); p += __shfl_xor(p, 4);
    p *= 0.17677669529663687f;               // 1/sqrt(32)

    float sc[8];
    #pragma unroll
    for (int i = 0; i < 8; ++i) sc[i] = __shfl(p, i << 3);

    float m = -INFINITY; int cnt = 0;
    #pragma unroll
    for (int i = 0; i < 8; ++i)
        if (bv[i] > -1e37f) { ++cnt; if (sc[i] > m) m = sc[i]; }

    float wgt[8]; float Z = 0.f;
    #pragma unroll
    for (int i = 0; i < 8; ++i) {
        bool val = bv[i] > -1e37f;
        wgt[i] = val ? expf(sc[i] - m) : 0.f;
        Z += wgt[i];
    }
    float invZ = (cnt > 0) ? 1.f / Z : 0.f;

    if (lane < 8) {
        selw[(rid << 3) + lane] = wgt[lane] * invZ;
        int gg = (bv[lane] > -1e37f) ? ((b << 12) + bi[lane]) : (b << 12);
        if (cnt == 0 && lane == 0) gg = -1;  // uniform-attention flag (t==0)
        selg[(rid << 3) + lane] = gg;
    }
}

// ---------------- K3b: wave-per-row streaming message + gelu epilogue --------
__global__ __launch_bounds__(256) void msg_kernel(const float* __restrict__ x,
        const float* __restrict__ meansum,
        const float* __restrict__ selw, const int* __restrict__ selg,
        const float* __restrict__ gain, const float* __restrict__ bias,
        const float* __restrict__ plm, const float* __restrict__ pls,
        float* __restrict__ out)
{
    int tid = threadIdx.x;
    int w = tid >> 6, lane = tid & 63;
    int rid = (blockIdx.x << 2) + w;         // global row b*T+t
    int b = rid >> 12;

    float mix   = 1.f / (1.f + expf(-plm[0]));
    float scale = log1pf(expf(pls[0])) + 0.01f;
    const float onemix = 1.f - mix;

    float wgt[8]; int g[8];
    #pragma unroll
    for (int i = 0; i < 8; ++i) {
        wgt[i] = selw[(rid << 3) + i];
        g[i]   = selg[(rid << 3) + i];
    }
    bool uniform = (g[0] < 0);
    if (uniform) g[0] = b << 12;             // safe address, weight is 0

    const float* xt = x + (size_t)rid * D;
    float* ot = out + (size_t)rid * D;

    #pragma unroll 2
    for (int seg = 0; seg < 4; ++seg) {
        int d0 = (seg << 8) + (lane << 2);
        float4 xv = *(const float4*)(xt + d0);
        float4 g4 = *(const float4*)(gain + d0);
        float4 b4 = *(const float4*)(bias + d0);
        float4 msg;
        if (uniform) {
            float4 ms = *(const float4*)(meansum + (b << 10) + d0);
            msg.x = ms.x * (1.f / (float)T); msg.y = ms.y * (1.f / (float)T);
            msg.z = ms.z * (1.f / (float)T); msg.w = ms.w * (1.f / (float)T);
        } else {
            msg = (float4){0.f, 0.f, 0.f, 0.f};
            #pragma unroll
            for (int i = 0; i < 8; ++i) {
                float4 rv = *(const float4*)(x + (size_t)g[i] * D + d0);
                msg.x += wgt[i] * rv.x; msg.y += wgt[i] * rv.y;
                msg.z += wgt[i] * rv.z; msg.w += wgt[i] * rv.w;
            }
        }
        float zi[4] = {
            (mix * xv.x + onemix * msg.x) * g4.x + b4.x,
            (mix * xv.y + onemix * msg.y) * g4.y + b4.y,
            (mix * xv.z + onemix * msg.z) * g4.z + b4.z,
            (mix * xv.w + onemix * msg.w) * g4.w + b4.w };
        float4 o4;
        o4.x = 0.5f * zi[0] * (1.f + erff(zi[0] * 0.70710678118654752f)) * scale;
        o4.y = 0.5f * zi[1] * (1.f + erff(zi[1] * 0.70710678118654752f)) * scale;
        o4.z = 0.5f * zi[2] * (1.f + erff(zi[2] * 0.70710678118654752f)) * scale;
        o4.w = 0.5f * zi[3] * (1.f + erff(zi[3] * 0.70710678118654752f)) * scale;
        *(float4*)(ot + d0) = o4;
    }
}

extern "C" void kernel_launch(void* const* d_in, const int* in_sizes, int n_in,
                              void* d_out, int out_size, void* d_ws, size_t ws_size,
                              hipStream_t stream)
{
    const float* x    = (const float*)d_in[0];
    const float* Wq   = (const float*)d_in[1];
    const float* Wk   = (const float*)d_in[2];
    const float* gain = (const float*)d_in[3];
    const float* bias = (const float*)d_in[4];
    const float* plm  = (const float*)d_in[5];
    const float* pls  = (const float*)d_in[6];
    float* out = (float*)d_out;

    float* ws      = (float*)d_ws;
    float* q       = ws;                       // 262144
    float* k       = ws + 262144;              // 262144
    float* meansum = ws + 524288;              // 2048
    float* pvals   = ws + 526336;              // B*T*CPR = 3145728
    int*   pidx    = (int*)(ws + 3672064);     // 3145728
    __bf16* xhi    = (__bf16*)(ws + 6817792);  // B*T*D bf16 (4194304 float-slots)
    __bf16* xlo    = xhi + (size_t)B * T * D;
    __bf16* Whi    = xlo + (size_t)B * T * D;  // 64*1024 bf16
    __bf16* Wlo    = Whi + 64 * D;
    float* selw    = ws + 15271936;            // B*T*8 = 65536
    int*   selg    = (int*)(ws + 15337472);    // 65536
    // total ws use: ~61.6 MB

    hipMemsetAsync(meansum, 0, 2048 * sizeof(float), stream);
    conv_kernel<<<B * T * D / 2048, 256, 0, stream>>>(x, xhi, xlo);
    conv_kernel<<<16, 256, 0, stream>>>(Wq, Whi, Wlo);
    conv_kernel<<<16, 256, 0, stream>>>(Wk, Whi + 32 * D, Wlo + 32 * D);
    mean_kernel<<<128, 256, 0, stream>>>(x, meansum);
    qk_mfma_kernel<<<B * T / 128, 256, 0, stream>>>(xhi, xlo, Whi, Wlo, q, k);
    topk_mfma_kernel<<<B * NBLK, 256, 0, stream>>>(xhi, xlo, pvals, pidx);
    select_kernel<<<B * T / 4, 256, 0, stream>>>(x, q, k, pvals, pidx, selw, selg);
    msg_kernel<<<B * T / 4, 256, 0, stream>>>(x, meansum, selw, selg,
                                              gain, bias, plm, pls, out);
}

// Round 7
// 406.446 us; speedup vs baseline: 3.3957x; 1.1460x over previous
//
#include <hip/hip_runtime.h>
#include <math.h>

#define B 2
#define T 4096
#define D 1024
#define DH 32
#define TNB 32        // 128-row tiles per batch
#define NBLK 528      // TNB*(TNB+1)/2 causal tile pairs
#define NK 12         // per-chunk candidates kept (safety margin over 8)
#define CPR (32*NK)   // candidates per row = 384

typedef __bf16 bf16x8 __attribute__((ext_vector_type(8)));
typedef float f32x4 __attribute__((ext_vector_type(4)));

// ---------------- K_conv: src -> (hi, lo) bf16 split (2048 elems/block) -------
__global__ __launch_bounds__(256) void conv_kernel(const float* __restrict__ x,
        __bf16* __restrict__ xhi, __bf16* __restrict__ xlo)
{
    int i = (blockIdx.x * 256 + threadIdx.x) << 3;     // 8 floats/thread
    float4 a = *(const float4*)(x + i);
    float4 c = *(const float4*)(x + i + 4);
    float av[8] = {a.x, a.y, a.z, a.w, c.x, c.y, c.z, c.w};
    __bf16 h[8], l[8];
    #pragma unroll
    for (int j = 0; j < 8; ++j) {
        h[j] = (__bf16)av[j];
        l[j] = (__bf16)(av[j] - (float)h[j]);
    }
    *(float4*)(xhi + i) = *(float4*)h;
    *(float4*)(xlo + i) = *(float4*)l;
}

// ---------------- K0: per-batch column sums (for the t=0 row) ----------------
__global__ void mean_kernel(const float* __restrict__ x, float* __restrict__ meansum)
{
    int gid  = blockIdx.x;           // B * 4 dblk * 16 tch = 128 blocks
    int b    = gid >> 6;
    int rem  = gid & 63;
    int dblk = rem >> 4;
    int tch  = rem & 15;
    int d = dblk * 256 + threadIdx.x;
    const float* xp = x + (b * T + tch * 256) * D + d;
    float s = 0.f;
    #pragma unroll 8
    for (int it = 0; it < 256; ++it) s += xp[it * D];
    atomicAdd(&meansum[(b << 10) + d], s);
}

// ---------------- K1: q/k projection as split-bf16 MFMA GEMM -----------------
__global__ __launch_bounds__(256) void qk_mfma_kernel(
        const __bf16* __restrict__ xhi, const __bf16* __restrict__ xlo,
        const __bf16* __restrict__ Whi, const __bf16* __restrict__ Wlo,
        float* __restrict__ qo, float* __restrict__ ko)
{
    __shared__ __align__(16) __bf16 stg[15360];
    __bf16* sAhi = stg;            // 128 x 40
    __bf16* sAlo = stg + 5120;
    __bf16* sBhi = stg + 10240;    // 64 x 40
    __bf16* sBlo = stg + 12800;

    int tid = threadIdx.x;
    int m0 = blockIdx.x << 7;
    int w = tid >> 6, lane = tid & 63;
    int fr = lane & 15, fq = lane >> 4;

    int arow = tid >> 1, ah = tid & 1;      // A staging: 2 chunks of 16 bf16
    int brow = tid >> 2, bq = tid & 3;      // B staging: 4 chunks of 8 bf16

    const __bf16* gAh = xhi + (size_t)(m0 + arow) * D + ah * 16;
    const __bf16* gAl = xlo + (size_t)(m0 + arow) * D + ah * 16;
    const __bf16* gBh = Whi + brow * D + bq * 8;
    const __bf16* gBl = Wlo + brow * D + bq * 8;

    f32x4 acc[2][4];
    #pragma unroll
    for (int i = 0; i < 2; ++i)
        #pragma unroll
        for (int j = 0; j < 4; ++j) acc[i][j] = (f32x4){0.f, 0.f, 0.f, 0.f};

    float4 a0 = *(const float4*)(gAh);
    float4 a1 = *(const float4*)(gAh + 8);
    float4 a2 = *(const float4*)(gAl);
    float4 a3 = *(const float4*)(gAl + 8);
    float4 b0 = *(const float4*)(gBh);
    float4 b1 = *(const float4*)(gBl);

    int sa = arow * 40 + ah * 16;
    int sb = brow * 40 + bq * 8;

    for (int kc = 0; kc < 32; ++kc) {
        __syncthreads();
        *(float4*)(sAhi + sa) = a0;  *(float4*)(sAhi + sa + 8) = a1;
        *(float4*)(sAlo + sa) = a2;  *(float4*)(sAlo + sa + 8) = a3;
        *(float4*)(sBhi + sb) = b0;  *(float4*)(sBlo + sb) = b1;
        if (kc + 1 < 32) {
            int k0 = (kc + 1) << 5;
            a0 = *(const float4*)(gAh + k0);
            a1 = *(const float4*)(gAh + k0 + 8);
            a2 = *(const float4*)(gAl + k0);
            a3 = *(const float4*)(gAl + k0 + 8);
            b0 = *(const float4*)(gBh + k0);
            b1 = *(const float4*)(gBl + k0);
        }
        __syncthreads();
        bf16x8 fah[2], fal[2], fbh[4], fbl[4];
        #pragma unroll
        for (int i = 0; i < 2; ++i) {
            int r = (w << 5) + i * 16 + fr;
            fah[i] = *(const bf16x8*)(sAhi + r * 40 + fq * 8);
            fal[i] = *(const bf16x8*)(sAlo + r * 40 + fq * 8);
        }
        #pragma unroll
        for (int j = 0; j < 4; ++j) {
            int r = j * 16 + fr;
            fbh[j] = *(const bf16x8*)(sBhi + r * 40 + fq * 8);
            fbl[j] = *(const bf16x8*)(sBlo + r * 40 + fq * 8);
        }
        #pragma unroll
        for (int i = 0; i < 2; ++i)
            #pragma unroll
            for (int j = 0; j < 4; ++j) {
                acc[i][j] = __builtin_amdgcn_mfma_f32_16x16x32_bf16(fah[i], fbh[j], acc[i][j], 0, 0, 0);
                acc[i][j] = __builtin_amdgcn_mfma_f32_16x16x32_bf16(fah[i], fbl[j], acc[i][j], 0, 0, 0);
                acc[i][j] = __builtin_amdgcn_mfma_f32_16x16x32_bf16(fal[i], fbh[j], acc[i][j], 0, 0, 0);
            }
    }
    // writeout: C layout col=lane&15, row=fq*4+reg
    #pragma unroll
    for (int i = 0; i < 2; ++i) {
        int grow0 = m0 + (w << 5) + i * 16 + (fq << 2);
        #pragma unroll
        for (int j = 0; j < 4; ++j) {
            int gn = j * 16 + fr;
            float* dst = (gn < 32) ? (qo + grow0 * DH + gn)
                                   : (ko + grow0 * DH + gn - 32);
            dst[0]      = acc[i][j][0];
            dst[DH]     = acc[i][j][1];
            dst[2 * DH] = acc[i][j][2];
            dst[3 * DH] = acc[i][j][3];
        }
    }
}

// ---------------- K2: hi-only bf16 MFMA sim GEMM + per-row top-12 per 128-col chunk
// Candidate filter only: exact fp32 re-rank downstream absorbs the ~0.03-dot-unit
// bf16 rounding error (gap rank8->rank13 is ~4 dot units => >100 sigma margin).
__global__ __launch_bounds__(256, 2) void topk_mfma_kernel(
        const __bf16* __restrict__ xhi,
        float* __restrict__ pvals, int* __restrict__ pidx)
{
    __shared__ __align__(16) float Sbuf[128 * 129];    // 66048 B
    __bf16* stg = (__bf16*)Sbuf;
    __bf16* sA = stg;                // 128 x 40
    __bf16* sB = stg + 5120;         // 128 x 40

    int tid = threadIdx.x;
    int b = blockIdx.x / NBLK;
    int l = blockIdx.x - b * NBLK;
    int rt = (int)((sqrtf(8.f * l + 1.f) - 1.f) * 0.5f);
    while ((rt + 1) * (rt + 2) / 2 <= l) ++rt;
    while (rt * (rt + 1) / 2 > l) --rt;
    int ct = l - rt * (rt + 1) / 2;
    int r0 = rt << 7, c0 = ct << 7;
    int base = b * T;

    int w = tid >> 6, lane = tid & 63;
    int wr = (w >> 1) << 6, wc = (w & 1) << 6;
    bool active = !(rt == ct && w == 1);   // diag block, fully non-causal quadrant

    int srow = tid >> 2, sq = tid & 3;     // staging: thread -> (row, 16B chunk)
    int fr = lane & 15, fq = lane >> 4;    // fragment: row-in-tile, k-quad

    const __bf16* gA = xhi + (base + r0) * D;
    const __bf16* gB = xhi + (base + c0) * D;

    f32x4 acc[4][4];
    #pragma unroll
    for (int i = 0; i < 4; ++i)
        #pragma unroll
        for (int j = 0; j < 4; ++j) acc[i][j] = (f32x4){0.f, 0.f, 0.f, 0.f};

    int o0 = srow * D + sq * 8;
    int o1 = o0 + 64 * D;
    float4 pf0 = *(const float4*)(gA + o0);
    float4 pf1 = *(const float4*)(gA + o1);
    float4 pf4 = *(const float4*)(gB + o0);
    float4 pf5 = *(const float4*)(gB + o1);

    int s0 = srow * 40 + sq * 8;
    int s1 = s0 + 64 * 40;

    for (int kc = 0; kc < 32; ++kc) {
        __syncthreads();
        *(float4*)(sA + s0) = pf0;  *(float4*)(sA + s1) = pf1;
        *(float4*)(sB + s0) = pf4;  *(float4*)(sB + s1) = pf5;
        if (kc + 1 < 32) {
            int k0 = (kc + 1) << 5;
            int n0 = srow * D + k0 + sq * 8;
            int n1 = n0 + 64 * D;
            pf0 = *(const float4*)(gA + n0);
            pf1 = *(const float4*)(gA + n1);
            pf4 = *(const float4*)(gB + n0);
            pf5 = *(const float4*)(gB + n1);
        }
        __syncthreads();
        if (active) {
            bf16x8 ah[4], bh[4];
            #pragma unroll
            for (int i = 0; i < 4; ++i) {
                int ar = wr + i * 16 + fr;
                ah[i] = *(const bf16x8*)(sA + ar * 40 + fq * 8);
                int bc = wc + i * 16 + fr;
                bh[i] = *(const bf16x8*)(sB + bc * 40 + fq * 8);
            }
            #pragma unroll
            for (int i = 0; i < 4; ++i)
                #pragma unroll
                for (int j = 0; j < 4; ++j)
                    acc[i][j] = __builtin_amdgcn_mfma_f32_16x16x32_bf16(ah[i], bh[j], acc[i][j], 0, 0, 0);
        }
    }
    __syncthreads();
    {   // write S: C layout col=lane&15, row=(lane>>4)*4+reg
        int cr = fq << 2, cc = fr;
        #pragma unroll
        for (int i = 0; i < 4; ++i)
            #pragma unroll
            for (int j = 0; j < 4; ++j) {
                float* sp = Sbuf + (wr + i * 16 + cr) * 129 + wc + j * 16 + cc;
                sp[0]       = acc[i][j][0];
                sp[129]     = acc[i][j][1];
                sp[2 * 129] = acc[i][j][2];
                sp[3 * 129] = acc[i][j][3];
            }
    }
    __syncthreads();
    if (tid < 128) {                       // per-row top-12 over this 128-col chunk
        int gt = r0 + tid;
        int cmax = gt - c0;
        if (cmax > 128) cmax = 128;
        if (cmax < 0) cmax = 0;
        float tv[NK]; int ti[NK];
        #pragma unroll
        for (int i = 0; i < NK; ++i) { tv[i] = -INFINITY; ti[i] = -1; }
        float vmin = -INFINITY; int minp = 0;
        const float* Srow = Sbuf + tid * 129;
        for (int c = 0; c < cmax; ++c) {
            float v = Srow[c];
            if (v > vmin) {
                tv[minp] = v; ti[minp] = c0 + c;
                vmin = tv[0]; minp = 0;
                #pragma unroll
                for (int i = 1; i < NK; ++i)
                    if (tv[i] < vmin) { vmin = tv[i]; minp = i; }
            }
        }
        int ob = (base + gt) * CPR + ct * NK;
        #pragma unroll
        for (int i = 0; i < NK; ++i) { pvals[ob + i] = tv[i]; pidx[ob + i] = ti[i]; }
    }
}

// ---------------- K3a: wave-per-row selection (barrier-free) ------------------
__global__ __launch_bounds__(256) void select_kernel(const float* __restrict__ x,
        const float* __restrict__ q, const float* __restrict__ k,
        const float* __restrict__ pvals, const int* __restrict__ pidx,
        float* __restrict__ selw, int* __restrict__ selg)
{
    int tid = threadIdx.x;
    int w = tid >> 6, lane = tid & 63;
    int rid = (blockIdx.x << 2) + w;         // global row b*T+t
    int b = rid >> 12, t = rid & (T - 1);
    int ncand = NK * ((t + 127) >> 7);

    // candidate loads (all in flight)
    float cv[6]; int ci[6];
    #pragma unroll
    for (int u = 0; u < 6; ++u) {
        int cid = lane + (u << 6);
        bool val = cid < ncand;
        cv[u] = val ? pvals[(size_t)rid * CPR + cid] : -INFINITY;
        ci[u] = val ? pidx[(size_t)rid * CPR + cid] : -1;
    }
    // prefetch xt fragments (independent of merge)
    const float* xt = x + (size_t)rid * D;
    float4 xt4[4];
    #pragma unroll
    for (int c = 0; c < 4; ++c)
        xt4[c] = *(const float4*)(xt + (c << 8) + (lane << 2));

    // butterfly merge -> approx top-12 (identical logic/tie-breaks)
    float sv[NK]; int si[NK];
    #pragma unroll
    for (int i = 0; i < NK; ++i) {
        float mv = cv[0]; int mi = ci[0];
        #pragma unroll
        for (int u = 1; u < 6; ++u)
            if (cv[u] > mv || (cv[u] == mv && ci[u] < mi)) { mv = cv[u]; mi = ci[u]; }
        #pragma unroll
        for (int off = 32; off >= 1; off >>= 1) {
            float ov = __shfl_xor(mv, off);
            int   oi = __shfl_xor(mi, off);
            if (ov > mv || (ov == mv && oi < mi)) { mv = ov; mi = oi; }
        }
        sv[i] = mv; si[i] = mi;
        #pragma unroll
        for (int u = 0; u < 6; ++u)
            if (cv[u] == mv && ci[u] == mi) cv[u] = -INFINITY;
    }

    // exact fp32 re-rank: 4 batches of 3 candidates, loads batched in flight
    float ex[NK];
    #pragma unroll
    for (int batch = 0; batch < 4; ++batch) {
        float4 rv[3][4];
        #pragma unroll
        for (int s = 0; s < 3; ++s) {
            int i = batch * 3 + s;
            int sj = si[i];
            const float* xj = x + (size_t)((b << 12) + (sj >= 0 ? sj : 0)) * D;
            #pragma unroll
            for (int c = 0; c < 4; ++c)
                rv[s][c] = *(const float4*)(xj + (c << 8) + (lane << 2));
        }
        #pragma unroll
        for (int s = 0; s < 3; ++s) {
            float ss = 0.f;
            #pragma unroll
            for (int c = 0; c < 4; ++c)
                ss += xt4[c].x * rv[s][c].x + xt4[c].y * rv[s][c].y
                    + xt4[c].z * rv[s][c].z + xt4[c].w * rv[s][c].w;
            ex[batch * 3 + s] = ss;
        }
    }
    // shuffle-reduce all 12 (independent chains pipeline)
    #pragma unroll
    for (int i = 0; i < NK; ++i) {
        float ssum = ex[i];
        #pragma unroll
        for (int off = 32; off >= 1; off >>= 1) ssum += __shfl_xor(ssum, off);
        ex[i] = (si[i] >= 0) ? ssum : -INFINITY;
    }

    // exact top-8 (tie-break: lower index) — every lane computes identically
    float bv[8]; int bi[8];
    #pragma unroll
    for (int r = 0; r < 8; ++r) {
        int mp = 0;
        #pragma unroll
        for (int i = 1; i < NK; ++i) {
            bool better = (ex[i] > ex[mp]) ||
                          (ex[i] == ex[mp] && si[i] >= 0 &&
                           (si[mp] < 0 || si[i] < si[mp]));
            if (better) mp = i;
        }
        bv[r] = ex[mp]; bi[r] = si[mp];
        ex[mp] = -INFINITY;
    }

    // scores: lanes 8i..8i+7 compute dot(q[t], k[sel_i])
    int i8 = lane >> 3, e = lane & 7;
    bool v8 = bv[i8] > -1e37f;
    int g8 = v8 ? bi[i8] : 0;
    float4 qv = *(const float4*)(q + (size_t)rid * DH + (e << 2));
    float4 kv = *(const float4*)(k + (size_t)((b << 12) + g8) * DH + (e << 2));
    float p = qv.x * kv.x + qv.y * kv.y + qv.z * kv.z + qv.w * kv.w;
    p += __shfl_xor(p, 1); p += __shfl_xor(p, 2); p += __shfl_xor(p, 4);
    p *= 0.17677669529663687f;               // 1/sqrt(32)

    float sc[8];
    #pragma unroll
    for (int i = 0; i < 8; ++i) sc[i] = __shfl(p, i << 3);

    float m = -INFINITY; int cnt = 0;
    #pragma unroll
    for (int i = 0; i < 8; ++i)
        if (bv[i] > -1e37f) { ++cnt; if (sc[i] > m) m = sc[i]; }

    float wgt[8]; float Z = 0.f;
    #pragma unroll
    for (int i = 0; i < 8; ++i) {
        bool val = bv[i] > -1e37f;
        wgt[i] = val ? expf(sc[i] - m) : 0.f;
        Z += wgt[i];
    }
    float invZ = (cnt > 0) ? 1.f / Z : 0.f;

    if (lane < 8) {
        selw[(rid << 3) + lane] = wgt[lane] * invZ;
        int gg = (bv[lane] > -1e37f) ? ((b << 12) + bi[lane]) : (b << 12);
        if (cnt == 0 && lane == 0) gg = -1;  // uniform-attention flag (t==0)
        selg[(rid << 3) + lane] = gg;
    }
}

// ---------------- K3b: wave-per-row streaming message + gelu epilogue --------
__global__ __launch_bounds__(256) void msg_kernel(const float* __restrict__ x,
        const float* __restrict__ meansum,
        const float* __restrict__ selw, const int* __restrict__ selg,
        const float* __restrict__ gain, const float* __restrict__ bias,
        const float* __restrict__ plm, const float* __restrict__ pls,
        float* __restrict__ out)
{
    int tid = threadIdx.x;
    int w = tid >> 6, lane = tid & 63;
    int rid = (blockIdx.x << 2) + w;         // global row b*T+t
    int b = rid >> 12;

    float mix   = 1.f / (1.f + expf(-plm[0]));
    float scale = log1pf(expf(pls[0])) + 0.01f;
    const float onemix = 1.f - mix;

    float wgt[8]; int g[8];
    #pragma unroll
    for (int i = 0; i < 8; ++i) {
        wgt[i] = selw[(rid << 3) + i];
        g[i]   = selg[(rid << 3) + i];
    }
    bool uniform = (g[0] < 0);
    if (uniform) g[0] = b << 12;             // safe address, weight is 0

    const float* xt = x + (size_t)rid * D;
    float* ot = out + (size_t)rid * D;

    #pragma unroll 2
    for (int seg = 0; seg < 4; ++seg) {
        int d0 = (seg << 8) + (lane << 2);
        float4 xv = *(const float4*)(xt + d0);
        float4 g4 = *(const float4*)(gain + d0);
        float4 b4 = *(const float4*)(bias + d0);
        float4 msg;
        if (uniform) {
            float4 ms = *(const float4*)(meansum + (b << 10) + d0);
            msg.x = ms.x * (1.f / (float)T); msg.y = ms.y * (1.f / (float)T);
            msg.z = ms.z * (1.f / (float)T); msg.w = ms.w * (1.f / (float)T);
        } else {
            msg = (float4){0.f, 0.f, 0.f, 0.f};
            #pragma unroll
            for (int i = 0; i < 8; ++i) {
                float4 rv = *(const float4*)(x + (size_t)g[i] * D + d0);
                msg.x += wgt[i] * rv.x; msg.y += wgt[i] * rv.y;
                msg.z += wgt[i] * rv.z; msg.w += wgt[i] * rv.w;
            }
        }
        float zi[4] = {
            (mix * xv.x + onemix * msg.x) * g4.x + b4.x,
            (mix * xv.y + onemix * msg.y) * g4.y + b4.y,
            (mix * xv.z + onemix * msg.z) * g4.z + b4.z,
            (mix * xv.w + onemix * msg.w) * g4.w + b4.w };
        float4 o4;
        o4.x = 0.5f * zi[0] * (1.f + erff(zi[0] * 0.70710678118654752f)) * scale;
        o4.y = 0.5f * zi[1] * (1.f + erff(zi[1] * 0.70710678118654752f)) * scale;
        o4.z = 0.5f * zi[2] * (1.f + erff(zi[2] * 0.70710678118654752f)) * scale;
        o4.w = 0.5f * zi[3] * (1.f + erff(zi[3] * 0.70710678118654752f)) * scale;
        *(float4*)(ot + d0) = o4;
    }
}

extern "C" void kernel_launch(void* const* d_in, const int* in_sizes, int n_in,
                              void* d_out, int out_size, void* d_ws, size_t ws_size,
                              hipStream_t stream)
{
    const float* x    = (const float*)d_in[0];
    const float* Wq   = (const float*)d_in[1];
    const float* Wk   = (const float*)d_in[2];
    const float* gain = (const float*)d_in[3];
    const float* bias = (const float*)d_in[4];
    const float* plm  = (const float*)d_in[5];
    const float* pls  = (const float*)d_in[6];
    float* out = (float*)d_out;

    float* ws      = (float*)d_ws;
    float* q       = ws;                       // 262144
    float* k       = ws + 262144;              // 262144
    float* meansum = ws + 524288;              // 2048
    float* pvals   = ws + 526336;              // B*T*CPR = 3145728
    int*   pidx    = (int*)(ws + 3672064);     // 3145728
    __bf16* xhi    = (__bf16*)(ws + 6817792);  // B*T*D bf16 (4194304 float-slots)
    __bf16* xlo    = xhi + (size_t)B * T * D;
    __bf16* Whi    = xlo + (size_t)B * T * D;  // 64*1024 bf16
    __bf16* Wlo    = Whi + 64 * D;
    float* selw    = ws + 15271936;            // B*T*8 = 65536
    int*   selg    = (int*)(ws + 15337472);    // 65536
    // total ws use: ~61.6 MB

    hipMemsetAsync(meansum, 0, 2048 * sizeof(float), stream);
    conv_kernel<<<B * T * D / 2048, 256, 0, stream>>>(x, xhi, xlo);
    conv_kernel<<<16, 256, 0, stream>>>(Wq, Whi, Wlo);
    conv_kernel<<<16, 256, 0, stream>>>(Wk, Whi + 32 * D, Wlo + 32 * D);
    mean_kernel<<<128, 256, 0, stream>>>(x, meansum);
    qk_mfma_kernel<<<B * T / 128, 256, 0, stream>>>(xhi, xlo, Whi, Wlo, q, k);
    topk_mfma_kernel<<<B * NBLK, 256, 0, stream>>>(xhi, pvals, pidx);
    select_kernel<<<B * T / 4, 256, 0, stream>>>(x, q, k, pvals, pidx, selw, selg);
    msg_kernel<<<B * T / 4, 256, 0, stream>>>(x, meansum, selw, selg,
                                              gain, bias, plm, pls, out);
}